// Round 2
// baseline (3204.327 us; speedup 1.0000x reference)
//
#include <hip/hip_runtime.h>
#include <math.h>

#define GAMMA_   0.97f
#define LAM_     0.95f
#define EPSILON_ 0.3f
#define HLOG2PI_ 0.91893853320467274f
#define LOG2C_   0.69314718055994531f
#define LOG1P2_  0.18232155679395463f
#define LOG0P8_  (-0.22314355131420976f)

constexpr int  TT     = 1024;
constexpr int  OBSF   = 64;
constexpr long ROWS_P = (long)TT * 256;          // 262144
constexpr long ROWS_V = (long)(TT + 1) * 256;    // 262400

// ---- workspace layout (float offsets) ----
constexpr long WS_W0T_P = 0;                       // [64][256]
constexpr long WS_W1T_P = WS_W0T_P + 64 * 256;     // [256][256]
constexpr long WS_W2T_P = WS_W1T_P + 256 * 256;    // [256][16]
constexpr long WS_W0T_V = WS_W2T_P + 256 * 16;     // [64][256]
constexpr long WS_W1T_V = WS_W0T_V + 64 * 256;     // [256][256]
constexpr long WS_INV   = WS_W1T_V + 256 * 256;    // 64
constexpr long WS_ACC   = WS_INV + 64;             // 32 accumulator slots
constexpr long WS_ADV   = WS_ACC + 32;             // 262144
constexpr long WS_BASE  = WS_ADV + ROWS_P;         // 262400
constexpr long WS_GA    = WS_BASE + ROWS_V;        // 32*256
constexpr long WS_GPR   = WS_GA + 32 * 256;        // 32*256
constexpr long WS_GS    = WS_GPR + 32 * 256;       // 32*256
// total ~720K floats (~2.9 MB)

// accum slots: 0 kl_sum, 1 kl_m_sum, 2 ent_sum, 3 adv_sum, 4 adv2_sum,
//              5 vmx2_sum, 6 gp_sum, 7 lp_sum

__device__ __forceinline__ float softplus_f(float x) {
  return (x > 20.f) ? x : log1pf(expf(x));
}
__device__ __forceinline__ float silu_f(float x) {
  return x / (1.f + __expf(-x));
}
__device__ __forceinline__ float clamp30(float x) {
  return fminf(1e30f, fmaxf(-1e30f, x));   // also maps NaN -> -1e30 (finite)
}

// ---------------- prep ----------------
__global__ void prep_kernel(const float* __restrict__ rv,
                            float* __restrict__ inv_std,
                            float* __restrict__ accum) {
  int t = threadIdx.x;
  if (t < 32) accum[t] = 0.f;
  if (t < 64) {
    float var = rv[t] / 1000001.0f;
    var = fminf(1e6f, fmaxf(1e-6f, var));
    inv_std[t] = 1.f / sqrtf(var);
  }
}

// ---------------- transpose: out[C][R] = in[R][C] ----------------
__global__ void transpose_kernel(const float* __restrict__ in,
                                 float* __restrict__ out, int R, int C) {
  int idx = blockIdx.x * 256 + threadIdx.x;
  if (idx < R * C) {
    int r = idx / C, c = idx - r * C;
    out[c * R + r] = in[idx];
  }
}

constexpr int LDX  = 68;    // X row stride
constexpr int LDH1 = 260;   // H1 row stride
constexpr int LDH2 = 132;   // H2 half-tile row stride

// =====================================================================
// Policy kernel: 16 rows of obs (LDS rows 0..15) + same 16 rows of pobs
// (LDS rows 16..31) through the 3-layer MLP; epilogue computes KL terms
// and the fused final per-row loss math (needs GAE done first).
// =====================================================================
__global__ __launch_bounds__(256, 2)
void policy_kernel(const float* __restrict__ obs,
                   const float* __restrict__ pobs,
                   const float* __restrict__ rm,
                   const float* __restrict__ inv_std,
                   const float* __restrict__ W0T, const float* __restrict__ b0,
                   const float* __restrict__ W1T, const float* __restrict__ b1,
                   const float* __restrict__ W2T, const float* __restrict__ b2,
                   const float* __restrict__ logits,
                   const float* __restrict__ action,
                   const float* __restrict__ noise,
                   const float* __restrict__ adv,
                   float* __restrict__ accum) {
  __shared__ __align__(16) float X [32 * LDX ];   // 2176
  __shared__ __align__(16) float H1[32 * LDH1];   // 8320
  __shared__ __align__(16) float H2[32 * LDH2];   // 4224
  __shared__ __align__(16) float OUTT[512];
  __shared__ float red[80];

  const int tid = threadIdx.x;
  const long row0 = (long)blockIdx.x * 16;

  // ---- stage: rows 0..15 = normalized obs, 16..31 = normalized pobs ----
  #pragma unroll
  for (int it = 0; it < 8; ++it) {
    int flat = it * 256 + tid;          // 0..2047
    int i  = flat >> 10;                // 0 obs, 1 pobs
    int rr = (flat >> 6) & 15;
    int f  = flat & 63;
    const float* src = i ? pobs : obs;
    float v = src[(row0 + rr) * OBSF + f];
    v = fminf(5.f, fmaxf(-5.f, (v - rm[f]) * inv_std[f]));
    X[(i * 16 + rr) * LDX + f] = v;
  }
  __syncthreads();

  const int col = tid & 31;
  const int mt  = tid >> 5;      // 0..7
  const int n0  = col * 8;
  const int m0  = mt * 4;        // rows 0..28

  // ---- layer 1: H1[32][256] = silu(X[32][64] @ W0T + b0) ----
  float acc1[4][8];
  {
    float4 bb0 = *(const float4*)(b0 + n0);
    float4 bb1 = *(const float4*)(b0 + n0 + 4);
    #pragma unroll
    for (int r = 0; r < 4; ++r) {
      acc1[r][0]=bb0.x; acc1[r][1]=bb0.y; acc1[r][2]=bb0.z; acc1[r][3]=bb0.w;
      acc1[r][4]=bb1.x; acc1[r][5]=bb1.y; acc1[r][6]=bb1.z; acc1[r][7]=bb1.w;
    }
  }
  for (int k0 = 0; k0 < 64; k0 += 4) {
    float ax[4][4];
    #pragma unroll
    for (int r = 0; r < 4; ++r) {
      float4 t = *(const float4*)&X[(m0 + r) * LDX + k0];
      ax[r][0]=t.x; ax[r][1]=t.y; ax[r][2]=t.z; ax[r][3]=t.w;
    }
    #pragma unroll
    for (int dk = 0; dk < 4; ++dk) {
      float4 wlo = *(const float4*)&W0T[(k0 + dk) * 256 + n0];
      float4 whi = *(const float4*)&W0T[(k0 + dk) * 256 + n0 + 4];
      float wv[8] = {wlo.x,wlo.y,wlo.z,wlo.w,whi.x,whi.y,whi.z,whi.w};
      #pragma unroll
      for (int r = 0; r < 4; ++r)
        #pragma unroll
        for (int j = 0; j < 8; ++j)
          acc1[r][j] = fmaf(ax[r][dk], wv[j], acc1[r][j]);
    }
  }
  #pragma unroll
  for (int r = 0; r < 4; ++r) {
    float4 lo, hi;
    lo.x=silu_f(acc1[r][0]); lo.y=silu_f(acc1[r][1]);
    lo.z=silu_f(acc1[r][2]); lo.w=silu_f(acc1[r][3]);
    hi.x=silu_f(acc1[r][4]); hi.y=silu_f(acc1[r][5]);
    hi.z=silu_f(acc1[r][6]); hi.w=silu_f(acc1[r][7]);
    *(float4*)&H1[(m0 + r) * LDH1 + n0]     = lo;
    *(float4*)&H1[(m0 + r) * LDH1 + n0 + 4] = hi;
  }
  __syncthreads();

  // ---- layers 2+3 in two half-passes over hidden2 columns ----
  const int nq0  = col * 4;         // col within half [0,128)
  const int prow = tid & 31;        // layer-3 row
  const int op   = (tid >> 5) * 2;  // layer-3 output pair
  float c3a = b2[op], c3b = b2[op + 1];

  #pragma unroll
  for (int h = 0; h < 2; ++h) {
    float acc2[4][4];
    {
      float4 bb = *(const float4*)(b1 + h * 128 + nq0);
      #pragma unroll
      for (int r = 0; r < 4; ++r) {
        acc2[r][0]=bb.x; acc2[r][1]=bb.y; acc2[r][2]=bb.z; acc2[r][3]=bb.w;
      }
    }
    for (int k0 = 0; k0 < 256; k0 += 4) {
      float ax[4][4];
      #pragma unroll
      for (int r = 0; r < 4; ++r) {
        float4 t = *(const float4*)&H1[(m0 + r) * LDH1 + k0];
        ax[r][0]=t.x; ax[r][1]=t.y; ax[r][2]=t.z; ax[r][3]=t.w;
      }
      #pragma unroll
      for (int dk = 0; dk < 4; ++dk) {
        float4 w = *(const float4*)&W1T[(k0 + dk) * 256 + h * 128 + nq0];
        float wv[4] = {w.x, w.y, w.z, w.w};
        #pragma unroll
        for (int r = 0; r < 4; ++r)
          #pragma unroll
          for (int j = 0; j < 4; ++j)
            acc2[r][j] = fmaf(ax[r][dk], wv[j], acc2[r][j]);
      }
    }
    #pragma unroll
    for (int r = 0; r < 4; ++r) {
      float4 o;
      o.x=silu_f(acc2[r][0]); o.y=silu_f(acc2[r][1]);
      o.z=silu_f(acc2[r][2]); o.w=silu_f(acc2[r][3]);
      *(float4*)&H2[(m0 + r) * LDH2 + nq0] = o;
    }
    __syncthreads();
    // layer-3 partial over this half's 128 k
    for (int k0 = 0; k0 < 128; k0 += 4) {
      float4 hv = *(const float4*)&H2[prow * LDH2 + k0];
      float hh[4] = {hv.x, hv.y, hv.z, hv.w};
      #pragma unroll
      for (int dk = 0; dk < 4; ++dk) {
        float2 w = *(const float2*)&W2T[(h * 128 + k0 + dk) * 16 + op];
        c3a = fmaf(hh[dk], w.x, c3a);
        c3b = fmaf(hh[dk], w.y, c3b);
      }
    }
    __syncthreads();   // protect H2 before next half overwrites
  }

  OUTT[prow * 16 + op]     = c3a;
  OUTT[prow * 16 + op + 1] = c3b;
  __syncthreads();

  // ---- epilogue: per-row KL + fused final loss math ----
  if (tid < 16) {
    int r = tid;
    long row = row0 + r;
    const float* arow = action + row * 8;
    const float* lrow = logits + row * 16;
    const float* nrow = noise  + row * 8;

    float glp = 0.f, llp = 0.f, kl = 0.f, blp = 0.f, ent = 0.f;
    #pragma unroll
    for (int d = 0; d < 8; ++d) {
      float gl  = OUTT[r * 16 + d];
      float gsr = OUTT[r * 16 + 8 + d];
      float ll  = OUTT[(16 + r) * 16 + d];
      float lsr = OUTT[(16 + r) * 16 + 8 + d];
      float gs = softplus_f(gsr) + 1e-3f;
      float ls = softplus_f(lsr) + 1e-3f;
      float a  = arow[d];
      float ldj = 2.f * (LOG2C_ - a - softplus_f(-2.f * a));
      float lgs = logf(gs), lls = logf(ls);
      float zg = (a - gl) / gs;
      float zl = (a - ll) / ls;
      glp += -0.5f * zg * zg - lgs - HLOG2PI_ - ldj;
      llp += -0.5f * zl * zl - lls - HLOG2PI_ - ldj;
      float ratio = gs / ls;
      float vr = ratio * ratio;
      float t1 = (gl - ll) / ls; t1 *= t1;
      kl += 0.5f * (vr + t1 - 1.f) - (lgs - lls);  // log vr = 2(lgs - lls)

      float loc = lrow[d], sr = lrow[8 + d];
      float sc  = softplus_f(sr) + 1e-3f;
      float lsc = logf(sc);
      float z   = (a - loc) / sc;
      blp += -0.5f * z * z - lsc - HLOG2PI_ - ldj;
      float dist  = loc + sc * nrow[d];
      float ldj_d = 2.f * (LOG2C_ - dist - softplus_f(-2.f * dist));
      ent += 0.5f + HLOG2PI_ + lsc + ldj_d;
    }
    kl *= 0.125f;
    kl  = clamp30(kl);
    ent = clamp30(ent);

    float diff = glp - llp;
    float m = (diff > LOG1P2_ || diff < LOG0P8_) ? 1.f : 0.f;  // NaN -> 0

    float N = (float)ROWS_P;
    float sum = accum[3], sumsq = accum[4];
    float mean = sum / N;
    float var  = fmaxf((sumsq - sum * sum / N) / (N - 1.f), 0.f);
    float inv  = 1.f / (sqrtf(var) + 1e-5f);
    float a_n  = (adv[row] - mean) * inv;

    float rho = expf(fminf(glp - blp, 80.f));   // NaN arg -> 80 via fminf
    float cl  = fminf(LOG1P2_, fmaxf(LOG0P8_, diff));
    float rc  = expf(fminf(cl + llp - blp, 80.f));
    rc = fminf(1.f + EPSILON_, fmaxf(1.f - EPSILON_, rc));
    float gp = clamp30(fminf(rho * a_n, rc * a_n));

    float rho2 = expf(fminf(llp - blp, 10.f));
    float r2c  = fminf(1.f + EPSILON_, fmaxf(1.f - EPSILON_, rho2));
    float lp = clamp30(fminf(rho2 * a_n, r2c * a_n));

    red[r]      = kl;
    red[16 + r] = kl * m;
    red[32 + r] = ent;
    red[48 + r] = gp;
    red[64 + r] = lp;
  }
  __syncthreads();
  if (tid == 0) {
    float s0=0.f, s1=0.f, s2=0.f, s3=0.f, s4=0.f;
    for (int r = 0; r < 16; ++r) {
      s0 += red[r]; s1 += red[16+r]; s2 += red[32+r];
      s3 += red[48+r]; s4 += red[64+r];
    }
    atomicAdd(&accum[0], s0);
    atomicAdd(&accum[1], s1);
    atomicAdd(&accum[2], s2);
    atomicAdd(&accum[6], s3);
    atomicAdd(&accum[7], s4);
  }
}

// =====================================================================
// Value kernel: 32 rows of obs through the 3-layer MLP (OUT=1).
// =====================================================================
__global__ __launch_bounds__(256, 2)
void value_kernel(const float* __restrict__ obs,
                  const float* __restrict__ rm,
                  const float* __restrict__ inv_std,
                  const float* __restrict__ W0T, const float* __restrict__ b0,
                  const float* __restrict__ W1T, const float* __restrict__ b1,
                  const float* __restrict__ w2, const float* __restrict__ b2,
                  float* __restrict__ baseline) {
  __shared__ __align__(16) float X [32 * LDX ];
  __shared__ __align__(16) float H1[32 * LDH1];
  __shared__ __align__(16) float H2[32 * LDH2];
  __shared__ float red[256];

  const int tid = threadIdx.x;
  const long row0 = (long)blockIdx.x * 32;

  #pragma unroll
  for (int it = 0; it < 8; ++it) {
    int flat = it * 256 + tid;      // 32*64
    int rr = flat >> 6, f = flat & 63;
    float v = obs[(row0 + rr) * OBSF + f];
    v = fminf(5.f, fmaxf(-5.f, (v - rm[f]) * inv_std[f]));
    X[rr * LDX + f] = v;
  }
  __syncthreads();

  const int col = tid & 31;
  const int mt  = tid >> 5;
  const int n0  = col * 8;
  const int m0  = mt * 4;

  float acc1[4][8];
  {
    float4 bb0 = *(const float4*)(b0 + n0);
    float4 bb1 = *(const float4*)(b0 + n0 + 4);
    #pragma unroll
    for (int r = 0; r < 4; ++r) {
      acc1[r][0]=bb0.x; acc1[r][1]=bb0.y; acc1[r][2]=bb0.z; acc1[r][3]=bb0.w;
      acc1[r][4]=bb1.x; acc1[r][5]=bb1.y; acc1[r][6]=bb1.z; acc1[r][7]=bb1.w;
    }
  }
  for (int k0 = 0; k0 < 64; k0 += 4) {
    float ax[4][4];
    #pragma unroll
    for (int r = 0; r < 4; ++r) {
      float4 t = *(const float4*)&X[(m0 + r) * LDX + k0];
      ax[r][0]=t.x; ax[r][1]=t.y; ax[r][2]=t.z; ax[r][3]=t.w;
    }
    #pragma unroll
    for (int dk = 0; dk < 4; ++dk) {
      float4 wlo = *(const float4*)&W0T[(k0 + dk) * 256 + n0];
      float4 whi = *(const float4*)&W0T[(k0 + dk) * 256 + n0 + 4];
      float wv[8] = {wlo.x,wlo.y,wlo.z,wlo.w,whi.x,whi.y,whi.z,whi.w};
      #pragma unroll
      for (int r = 0; r < 4; ++r)
        #pragma unroll
        for (int j = 0; j < 8; ++j)
          acc1[r][j] = fmaf(ax[r][dk], wv[j], acc1[r][j]);
    }
  }
  #pragma unroll
  for (int r = 0; r < 4; ++r) {
    float4 lo, hi;
    lo.x=silu_f(acc1[r][0]); lo.y=silu_f(acc1[r][1]);
    lo.z=silu_f(acc1[r][2]); lo.w=silu_f(acc1[r][3]);
    hi.x=silu_f(acc1[r][4]); hi.y=silu_f(acc1[r][5]);
    hi.z=silu_f(acc1[r][6]); hi.w=silu_f(acc1[r][7]);
    *(float4*)&H1[(m0 + r) * LDH1 + n0]     = lo;
    *(float4*)&H1[(m0 + r) * LDH1 + n0 + 4] = hi;
  }
  __syncthreads();

  const int nq0 = col * 4;
  const int vrow = tid & 31;
  const int ks   = tid >> 5;
  float partial = 0.f;

  #pragma unroll
  for (int h = 0; h < 2; ++h) {
    float acc2[4][4];
    {
      float4 bb = *(const float4*)(b1 + h * 128 + nq0);
      #pragma unroll
      for (int r = 0; r < 4; ++r) {
        acc2[r][0]=bb.x; acc2[r][1]=bb.y; acc2[r][2]=bb.z; acc2[r][3]=bb.w;
      }
    }
    for (int k0 = 0; k0 < 256; k0 += 4) {
      float ax[4][4];
      #pragma unroll
      for (int r = 0; r < 4; ++r) {
        float4 t = *(const float4*)&H1[(m0 + r) * LDH1 + k0];
        ax[r][0]=t.x; ax[r][1]=t.y; ax[r][2]=t.z; ax[r][3]=t.w;
      }
      #pragma unroll
      for (int dk = 0; dk < 4; ++dk) {
        float4 w = *(const float4*)&W1T[(k0 + dk) * 256 + h * 128 + nq0];
        float wv[4] = {w.x, w.y, w.z, w.w};
        #pragma unroll
        for (int r = 0; r < 4; ++r)
          #pragma unroll
          for (int j = 0; j < 4; ++j)
            acc2[r][j] = fmaf(ax[r][dk], wv[j], acc2[r][j]);
      }
    }
    #pragma unroll
    for (int r = 0; r < 4; ++r) {
      float4 o;
      o.x=silu_f(acc2[r][0]); o.y=silu_f(acc2[r][1]);
      o.z=silu_f(acc2[r][2]); o.w=silu_f(acc2[r][3]);
      *(float4*)&H2[(m0 + r) * LDH2 + nq0] = o;
    }
    __syncthreads();
    #pragma unroll
    for (int q = 0; q < 16; q += 4) {
      int kl = ks * 16 + q;
      float4 hv = *(const float4*)&H2[vrow * LDH2 + kl];
      partial = fmaf(hv.x, w2[h * 128 + kl],     partial);
      partial = fmaf(hv.y, w2[h * 128 + kl + 1], partial);
      partial = fmaf(hv.z, w2[h * 128 + kl + 2], partial);
      partial = fmaf(hv.w, w2[h * 128 + kl + 3], partial);
    }
    __syncthreads();
  }

  red[ks * 32 + vrow] = partial;
  __syncthreads();
  if (tid < 32) {
    float s = b2[0];
    #pragma unroll
    for (int q = 0; q < 8; ++q) s += red[q * 32 + tid];
    baseline[row0 + tid] = s;
  }
}

// ---------------- GAE segmented scan ----------------
__global__ void gae_phase1(const float* __restrict__ reward,
                           const float* __restrict__ done,
                           const float* __restrict__ trunc,
                           const float* __restrict__ baseline,
                           float* __restrict__ A, float* __restrict__ P) {
  int s = blockIdx.x, b = threadIdx.x;
  float Aa = 0.f, Pp = 1.f;
  for (int t = (s + 1) * 32 - 1; t >= s * 32; --t) {
    int idx = t * 256 + b;
    float r = reward[idx], d = done[idx], tr = trunc[idx];
    float tm = 1.f - tr;
    float te = d * tm;
    float bl = baseline[idx], bl1 = baseline[idx + 256];
    float g1 = GAMMA_ * (1.f - te);
    float delta = (r + g1 * bl1 - bl) * tm;
    float c = g1 * tm * LAM_;
    Aa = delta + c * Aa;
    Pp = c * Pp;
  }
  A[s * 256 + b] = Aa;
  P[s * 256 + b] = Pp;
}

__global__ void gae_phase2(const float* __restrict__ A,
                           const float* __restrict__ P,
                           float* __restrict__ seedv) {
  int b = threadIdx.x;
  float acc = 0.f;
  for (int s = 31; s >= 0; --s) {
    seedv[s * 256 + b] = acc;
    acc = A[s * 256 + b] + P[s * 256 + b] * acc;
  }
}

__global__ void gae_phase3(const float* __restrict__ reward,
                           const float* __restrict__ done,
                           const float* __restrict__ trunc,
                           const float* __restrict__ baseline,
                           const float* __restrict__ seedv,
                           float* __restrict__ adv,
                           float* __restrict__ accum) {
  __shared__ float red[12];
  int s = blockIdx.x, b = threadIdx.x;
  float acc = seedv[s * 256 + b];
  int tend = (s + 1) * 32;
  float vnext = baseline[tend * 256 + b];   // bootstrap row for s=31
  float vs_next = acc + vnext;
  float sa = 0.f, sa2 = 0.f, sv2 = 0.f;
  for (int t = tend - 1; t >= s * 32; --t) {
    int idx = t * 256 + b;
    float r = reward[idx], d = done[idx], tr = trunc[idx];
    float tm = 1.f - tr;
    float te = d * tm;
    float bl = baseline[idx];
    float g1 = GAMMA_ * (1.f - te);
    float delta = (r + g1 * vnext - bl) * tm;
    acc = delta + g1 * tm * LAM_ * acc;
    float at = (r + g1 * vs_next - bl) * tm;
    at = fminf(1e15f, fmaxf(-1e15f, at));   // no-op in sane regime
    adv[idx] = at;
    sa += at; sa2 += at * at;
    sv2 += fminf(acc * acc, 1e30f);
    vs_next = acc + bl;
    vnext = bl;
  }
  // block reduce 3 sums
  float v0 = sa, v1 = sa2, v2 = sv2;
  #pragma unroll
  for (int o = 32; o > 0; o >>= 1) {
    v0 += __shfl_down(v0, o, 64);
    v1 += __shfl_down(v1, o, 64);
    v2 += __shfl_down(v2, o, 64);
  }
  int lane = threadIdx.x & 63, w = threadIdx.x >> 6;
  if (lane == 0) { red[w] = v0; red[4 + w] = v1; red[8 + w] = v2; }
  __syncthreads();
  if (threadIdx.x == 0) {
    float s0=0.f, s1=0.f, s2=0.f;
    for (int q = 0; q < 4; ++q) { s0 += red[q]; s1 += red[4+q]; s2 += red[8+q]; }
    atomicAdd(&accum[3], s0);
    atomicAdd(&accum[4], s1);
    atomicAdd(&accum[5], s2);
  }
}

// ---------------- finalize ----------------
__global__ void finalize_kernel(const float* __restrict__ accum,
                                float* __restrict__ out) {
  float N = (float)ROWS_P;
  float kl_learner = accum[0] / N;
  float kl_guider  = accum[1] / N;
  float entropy    = accum[2] / N;
  float v_loss     = 0.25f * accum[5] / N;
  float gp_loss    = -accum[6] / N;
  float lp_loss    = -accum[7] / N;
  float learner_loss = kl_learner + lp_loss;      // ALPHA = 1
  float guider_loss  = kl_guider + gp_loss;
  float total = learner_loss + guider_loss + v_loss - 0.01f * entropy;
  out[0] = total;
  out[1] = guider_loss;
  out[2] = learner_loss;
  out[3] = kl_learner;
}

extern "C" void kernel_launch(void* const* d_in, const int* in_sizes, int n_in,
                              void* d_out, int out_size, void* d_ws, size_t ws_size,
                              hipStream_t stream) {
  (void)in_sizes; (void)n_in; (void)out_size; (void)ws_size;
  const float* obs    = (const float*)d_in[0];
  const float* pobs   = (const float*)d_in[1];
  const float* reward = (const float*)d_in[2];
  const float* done   = (const float*)d_in[3];
  const float* trunc  = (const float*)d_in[4];
  const float* logits = (const float*)d_in[5];
  const float* action = (const float*)d_in[6];
  const float* noise  = (const float*)d_in[7];
  const float* pw0 = (const float*)d_in[8];
  const float* pb0 = (const float*)d_in[9];
  const float* pw1 = (const float*)d_in[10];
  const float* pb1 = (const float*)d_in[11];
  const float* pw2 = (const float*)d_in[12];
  const float* pb2 = (const float*)d_in[13];
  const float* vw0 = (const float*)d_in[14];
  const float* vb0 = (const float*)d_in[15];
  const float* vw1 = (const float*)d_in[16];
  const float* vb1 = (const float*)d_in[17];
  const float* vw2 = (const float*)d_in[18];
  const float* vb2 = (const float*)d_in[19];
  const float* rm  = (const float*)d_in[20];
  const float* rv  = (const float*)d_in[21];
  float* ws  = (float*)d_ws;
  float* out = (float*)d_out;

  float* W0T_p = ws + WS_W0T_P;
  float* W1T_p = ws + WS_W1T_P;
  float* W2T_p = ws + WS_W2T_P;
  float* W0T_v = ws + WS_W0T_V;
  float* W1T_v = ws + WS_W1T_V;
  float* inv_std = ws + WS_INV;
  float* accum = ws + WS_ACC;
  float* adv  = ws + WS_ADV;
  float* base = ws + WS_BASE;
  float* gA   = ws + WS_GA;
  float* gP   = ws + WS_GPR;
  float* gS   = ws + WS_GS;

  prep_kernel<<<1, 256, 0, stream>>>(rv, inv_std, accum);
  transpose_kernel<<<(256*64 + 255)/256, 256, 0, stream>>>(pw0, W0T_p, 256, 64);
  transpose_kernel<<<(256*256 + 255)/256, 256, 0, stream>>>(pw1, W1T_p, 256, 256);
  transpose_kernel<<<(16*256 + 255)/256, 256, 0, stream>>>(pw2, W2T_p, 16, 256);
  transpose_kernel<<<(256*64 + 255)/256, 256, 0, stream>>>(vw0, W0T_v, 256, 64);
  transpose_kernel<<<(256*256 + 255)/256, 256, 0, stream>>>(vw1, W1T_v, 256, 256);

  value_kernel<<<(int)(ROWS_V / 32), 256, 0, stream>>>(
      obs, rm, inv_std, W0T_v, vb0, W1T_v, vb1, vw2, vb2, base);

  gae_phase1<<<32, 256, 0, stream>>>(reward, done, trunc, base, gA, gP);
  gae_phase2<<<1, 256, 0, stream>>>(gA, gP, gS);
  gae_phase3<<<32, 256, 0, stream>>>(reward, done, trunc, base, gS, adv, accum);

  policy_kernel<<<(int)(ROWS_P / 16), 256, 0, stream>>>(
      obs, pobs, rm, inv_std, W0T_p, pb0, W1T_p, pb1, W2T_p, pb2,
      logits, action, noise, adv, accum);

  finalize_kernel<<<1, 1, 0, stream>>>(accum, out);
}

// Round 3
// 1631.700 us; speedup vs baseline: 1.9638x; 1.9638x over previous
//
#include <hip/hip_runtime.h>
#include <math.h>

#define GAMMA_   0.97f
#define LAM_     0.95f
#define EPSILON_ 0.3f
#define HLOG2PI_ 0.91893853320467274f
#define LOG2C_   0.69314718055994531f
#define LOG1P2_  0.18232155679395463f
#define LOG0P8_  (-0.22314355131420976f)

typedef unsigned short u16;
typedef unsigned int   u32;
typedef __attribute__((ext_vector_type(8))) short short8;
typedef __attribute__((ext_vector_type(4))) float floatx4;

constexpr int  TT     = 1024;
constexpr long ROWS_P = (long)TT * 256;          // 262144
constexpr long ROWS_V = (long)(TT + 1) * 256;    // 262400

// ---- fragment workspace layout (u16 offsets from ws base) ----
// frag arrays: [NT][KS][64 lanes][8] bf16, one dwordx4 per (ntile,kstep,lane)
constexpr long FR_W0P_HI = 0;        // NT16 KS2  -> 16384
constexpr long FR_W0P_LO = 16384;
constexpr long FR_W1P_HI = 32768;    // NT16 KS8  -> 65536
constexpr long FR_W1P_LO = 98304;
constexpr long FR_W2P_HI = 163840;   // NT1  KS8  -> 4096
constexpr long FR_W2P_LO = 167936;
constexpr long FR_W0V_HI = 172032;
constexpr long FR_W0V_LO = 188416;
constexpr long FR_W1V_HI = 204800;
constexpr long FR_W1V_LO = 270336;
constexpr long FR_W2V_HI = 335872;
constexpr long FR_W2V_LO = 339968;
constexpr long FR_TOTAL  = 344064;   // u16 elems = 172032 floats

// ---- float workspace (offsets from (float*)ws + FR_TOTAL/2) ----
constexpr long WS_ACC  = 0;                 // 32
constexpr long WS_INV  = 32;                // 64
constexpr long WS_ADV  = 96;                // 262144
constexpr long WS_BASE = WS_ADV + ROWS_P;   // 262400
constexpr long WS_GA   = WS_BASE + ROWS_V;  // 8192
constexpr long WS_GP   = WS_GA + 8192;
constexpr long WS_GS   = WS_GP + 8192;
// total floats = FR_TOTAL/2 + WS_GS + 8192 ~= 721K floats (~2.9 MB)

// accum slots: 0 kl_sum, 1 kl_m_sum, 2 ent_sum, 3 adv_sum, 4 adv2_sum,
//              5 vmx2_sum, 6 gp_sum, 7 lp_sum

__device__ __forceinline__ float softplus_f(float x) {
  return (x > 20.f) ? x : log1pf(expf(x));
}
__device__ __forceinline__ float silu_f(float x) {
  return x / (1.f + __expf(-x));
}
__device__ __forceinline__ float clamp30(float x) {
  return fminf(1e30f, fmaxf(-1e30f, x));
}
__device__ __forceinline__ u16 f2bf(float x) {      // RNE fp32 -> bf16
  u32 u = __float_as_uint(x);
  u32 r = (u + 0x7FFFu + ((u >> 16) & 1u)) >> 16;
  return (u16)r;
}
__device__ __forceinline__ float bf2f(u16 h) {
  return __uint_as_float(((u32)h) << 16);
}

// ---------------- prep ----------------
__global__ void prep_kernel(const float* __restrict__ rv,
                            float* __restrict__ inv_std,
                            float* __restrict__ accum) {
  int t = threadIdx.x;
  if (t < 32) accum[t] = 0.f;
  if (t < 64) {
    float var = rv[t] / 1000001.0f;
    var = fminf(1e6f, fmaxf(1e-6f, var));
    inv_std[t] = 1.f / sqrtf(var);
  }
}

// ---------------- weight -> split-bf16 MFMA fragments ----------------
// frag order: [NT][KS][lane][j]: value = W[n][k], n=nt*16+(lane&15),
// k=ks*32+(lane>>4)*8+j. W row-major [fout][fin] (exactly x@W.T layout).
__global__ void convert_kernel(const float* __restrict__ pw0,
                               const float* __restrict__ pw1,
                               const float* __restrict__ pw2,
                               const float* __restrict__ vw0,
                               const float* __restrict__ vw1,
                               const float* __restrict__ vw2,
                               u16* __restrict__ frag) {
  int idx = blockIdx.x * 256 + threadIdx.x;   // 0..172031
  const float* W; int kslog, K, nvalid; long hioff, looff; int e;
  if (idx < 16384)       { W = pw0; e = idx;          kslog = 1; K = 64;  nvalid = 256; hioff = FR_W0P_HI; looff = FR_W0P_LO; }
  else if (idx < 81920)  { W = pw1; e = idx - 16384;  kslog = 3; K = 256; nvalid = 256; hioff = FR_W1P_HI; looff = FR_W1P_LO; }
  else if (idx < 86016)  { W = pw2; e = idx - 81920;  kslog = 3; K = 256; nvalid = 16;  hioff = FR_W2P_HI; looff = FR_W2P_LO; }
  else if (idx < 102400) { W = vw0; e = idx - 86016;  kslog = 1; K = 64;  nvalid = 256; hioff = FR_W0V_HI; looff = FR_W0V_LO; }
  else if (idx < 167936) { W = vw1; e = idx - 102400; kslog = 3; K = 256; nvalid = 256; hioff = FR_W1V_HI; looff = FR_W1V_LO; }
  else                   { W = vw2; e = idx - 167936; kslog = 3; K = 256; nvalid = 1;   hioff = FR_W2V_HI; looff = FR_W2V_LO; }
  int j    = e & 7;
  int lane = (e >> 3) & 63;
  int ks   = (e >> 9) & ((1 << kslog) - 1);
  int nt   = e >> (9 + kslog);
  int n = nt * 16 + (lane & 15);
  int k = ks * 32 + ((lane >> 4) << 3) + j;
  float w = (n < nvalid) ? W[n * K + k] : 0.f;
  u16 hi = f2bf(w);
  frag[hioff + e] = hi;
  frag[looff + e] = f2bf(w - bf2f(hi));
}

// LDS strides (u16 units); both are multiples of 8 (16B-aligned rows)
constexpr int SX = 72;    // 64 k * 2B + 16B pad   (144 B)
constexpr int SH = 264;   // 256 k * 2B + 16B pad  (528 B)

// =====================================================================
// Policy: block = 16 obs rows (mtile 0) + same 16 pobs rows (mtile 1).
// 4 waves: wave(mt,nth) does mtile mt, ntile-half nth. Split-bf16 MFMA.
// =====================================================================
__global__ __launch_bounds__(256, 3)
void policy_kernel(const float* __restrict__ obs,
                   const float* __restrict__ pobs,
                   const float* __restrict__ rm,
                   const float* __restrict__ inv_std,
                   const u16* __restrict__ frag,
                   const float* __restrict__ b0,
                   const float* __restrict__ b1,
                   const float* __restrict__ b2,
                   const float* __restrict__ logits,
                   const float* __restrict__ action,
                   const float* __restrict__ noise,
                   const float* __restrict__ adv,
                   float* __restrict__ accum) {
  __shared__ __align__(16) u16 Xh[32 * SX], Xl[32 * SX];
  __shared__ __align__(16) u16 Hh[32 * SH], Hl[32 * SH];   // H1, then H2
  __shared__ float OUTT[32 * 16];
  __shared__ float red[80];

  const int tid  = threadIdx.x;
  const long row0 = (long)blockIdx.x * 16;
  const int lane = tid & 63;
  const int wv   = tid >> 6;
  const int mt   = wv >> 1;          // 0 obs rows, 1 pobs rows
  const int nth  = wv & 1;           // ntile half
  const int rowbase = mt * 16;
  const int lm = lane & 15;
  const int lq = lane >> 4;

  // ---- stage normalized X, split bf16 ----
  #pragma unroll
  for (int it = 0; it < 8; ++it) {
    int flat = it * 256 + tid;       // 32 rows * 64 f
    int rr = flat >> 6;
    int f  = flat & 63;
    const float* src = (rr < 16) ? obs : pobs;
    float v = src[(row0 + (rr & 15)) * 64 + f];
    v = fminf(5.f, fmaxf(-5.f, (v - rm[f]) * inv_std[f]));
    u16 hi = f2bf(v);
    Xh[rr * SX + f] = hi;
    Xl[rr * SX + f] = f2bf(v - bf2f(hi));
  }
  __syncthreads();

  floatx4 acc[8];

  // ---- layer 1: K=64 (2 ksteps) ----
  #pragma unroll
  for (int i = 0; i < 8; ++i) acc[i] = (floatx4){0.f, 0.f, 0.f, 0.f};
  {
    const short8* B0h = (const short8*)(frag + FR_W0P_HI);
    const short8* B0l = (const short8*)(frag + FR_W0P_LO);
    #pragma unroll
    for (int ks = 0; ks < 2; ++ks) {
      short8 Ah = *(const short8*)&Xh[(rowbase + lm) * SX + ks * 32 + lq * 8];
      short8 Al = *(const short8*)&Xl[(rowbase + lm) * SX + ks * 32 + lq * 8];
      #pragma unroll
      for (int nt = 0; nt < 8; ++nt) {
        int ntg = nth * 8 + nt;
        short8 Bh = B0h[(ntg * 2 + ks) * 64 + lane];
        short8 Bl = B0l[(ntg * 2 + ks) * 64 + lane];
        acc[nt] = __builtin_amdgcn_mfma_f32_16x16x32_bf16(Ah, Bh, acc[nt], 0, 0, 0);
        acc[nt] = __builtin_amdgcn_mfma_f32_16x16x32_bf16(Ah, Bl, acc[nt], 0, 0, 0);
        acc[nt] = __builtin_amdgcn_mfma_f32_16x16x32_bf16(Al, Bh, acc[nt], 0, 0, 0);
      }
    }
  }
  // write H1 = silu(acc + b0), split
  #pragma unroll
  for (int nt = 0; nt < 8; ++nt) {
    int col = (nth * 8 + nt) * 16 + lm;
    float bias = b0[col];
    #pragma unroll
    for (int reg = 0; reg < 4; ++reg) {
      int row = rowbase + lq * 4 + reg;
      float v = silu_f(acc[nt][reg] + bias);
      u16 hi = f2bf(v);
      Hh[row * SH + col] = hi;
      Hl[row * SH + col] = f2bf(v - bf2f(hi));
    }
  }
  __syncthreads();

  // ---- layer 2: K=256 (8 ksteps) ----
  #pragma unroll
  for (int i = 0; i < 8; ++i) acc[i] = (floatx4){0.f, 0.f, 0.f, 0.f};
  {
    const short8* B1h = (const short8*)(frag + FR_W1P_HI);
    const short8* B1l = (const short8*)(frag + FR_W1P_LO);
    for (int ks = 0; ks < 8; ++ks) {
      short8 Ah = *(const short8*)&Hh[(rowbase + lm) * SH + ks * 32 + lq * 8];
      short8 Al = *(const short8*)&Hl[(rowbase + lm) * SH + ks * 32 + lq * 8];
      #pragma unroll
      for (int nt = 0; nt < 8; ++nt) {
        int ntg = nth * 8 + nt;
        short8 Bh = B1h[(ntg * 8 + ks) * 64 + lane];
        short8 Bl = B1l[(ntg * 8 + ks) * 64 + lane];
        acc[nt] = __builtin_amdgcn_mfma_f32_16x16x32_bf16(Ah, Bh, acc[nt], 0, 0, 0);
        acc[nt] = __builtin_amdgcn_mfma_f32_16x16x32_bf16(Ah, Bl, acc[nt], 0, 0, 0);
        acc[nt] = __builtin_amdgcn_mfma_f32_16x16x32_bf16(Al, Bh, acc[nt], 0, 0, 0);
      }
    }
  }
  __syncthreads();          // all waves done READING H1 (H2 aliases it)
  #pragma unroll
  for (int nt = 0; nt < 8; ++nt) {
    int col = (nth * 8 + nt) * 16 + lm;
    float bias = b1[col];
    #pragma unroll
    for (int reg = 0; reg < 4; ++reg) {
      int row = rowbase + lq * 4 + reg;
      float v = silu_f(acc[nt][reg] + bias);
      u16 hi = f2bf(v);
      Hh[row * SH + col] = hi;
      Hl[row * SH + col] = f2bf(v - bf2f(hi));
    }
  }
  __syncthreads();

  // ---- layer 3: N=16, K=256 (waves with nth==0 only) ----
  if (nth == 0) {
    floatx4 c3 = (floatx4){0.f, 0.f, 0.f, 0.f};
    const short8* B2h = (const short8*)(frag + FR_W2P_HI);
    const short8* B2l = (const short8*)(frag + FR_W2P_LO);
    for (int ks = 0; ks < 8; ++ks) {
      short8 Ah = *(const short8*)&Hh[(rowbase + lm) * SH + ks * 32 + lq * 8];
      short8 Al = *(const short8*)&Hl[(rowbase + lm) * SH + ks * 32 + lq * 8];
      short8 Bh = B2h[ks * 64 + lane];
      short8 Bl = B2l[ks * 64 + lane];
      c3 = __builtin_amdgcn_mfma_f32_16x16x32_bf16(Ah, Bh, c3, 0, 0, 0);
      c3 = __builtin_amdgcn_mfma_f32_16x16x32_bf16(Ah, Bl, c3, 0, 0, 0);
      c3 = __builtin_amdgcn_mfma_f32_16x16x32_bf16(Al, Bh, c3, 0, 0, 0);
    }
    float bias = b2[lm];
    #pragma unroll
    for (int reg = 0; reg < 4; ++reg) {
      int row = rowbase + lq * 4 + reg;
      OUTT[row * 16 + lm] = c3[reg] + bias;
    }
  }
  __syncthreads();

  // ---- epilogue: per-row KL + fused final loss math ----
  if (tid < 16) {
    int r = tid;
    long row = row0 + r;
    const float* arow = action + row * 8;
    const float* lrow = logits + row * 16;
    const float* nrow = noise  + row * 8;

    float glp = 0.f, llp = 0.f, kl = 0.f, blp = 0.f, ent = 0.f;
    #pragma unroll
    for (int d = 0; d < 8; ++d) {
      float gl  = OUTT[r * 16 + d];
      float gsr = OUTT[r * 16 + 8 + d];
      float ll  = OUTT[(16 + r) * 16 + d];
      float lsr = OUTT[(16 + r) * 16 + 8 + d];
      float gs = softplus_f(gsr) + 1e-3f;
      float ls = softplus_f(lsr) + 1e-3f;
      float a  = arow[d];
      float ldj = 2.f * (LOG2C_ - a - softplus_f(-2.f * a));
      float lgs = logf(gs), lls = logf(ls);
      float zg = (a - gl) / gs;
      float zl = (a - ll) / ls;
      glp += -0.5f * zg * zg - lgs - HLOG2PI_ - ldj;
      llp += -0.5f * zl * zl - lls - HLOG2PI_ - ldj;
      float ratio = gs / ls;
      float vr = ratio * ratio;
      float t1 = (gl - ll) / ls; t1 *= t1;
      kl += 0.5f * (vr + t1 - 1.f) - (lgs - lls);

      float loc = lrow[d], sr = lrow[8 + d];
      float sc  = softplus_f(sr) + 1e-3f;
      float lsc = logf(sc);
      float z   = (a - loc) / sc;
      blp += -0.5f * z * z - lsc - HLOG2PI_ - ldj;
      float dist  = loc + sc * nrow[d];
      float ldj_d = 2.f * (LOG2C_ - dist - softplus_f(-2.f * dist));
      ent += 0.5f + HLOG2PI_ + lsc + ldj_d;
    }
    kl *= 0.125f;
    kl  = clamp30(kl);
    ent = clamp30(ent);

    float diff = glp - llp;
    float m = (diff > LOG1P2_ || diff < LOG0P8_) ? 1.f : 0.f;

    float N = (float)ROWS_P;
    float sum = accum[3], sumsq = accum[4];
    float mean = sum / N;
    float var  = fmaxf((sumsq - sum * sum / N) / (N - 1.f), 0.f);
    float inv  = 1.f / (sqrtf(var) + 1e-5f);
    float a_n  = (adv[row] - mean) * inv;

    float rho = expf(fminf(glp - blp, 80.f));
    float cl  = fminf(LOG1P2_, fmaxf(LOG0P8_, diff));
    float rc  = expf(fminf(cl + llp - blp, 80.f));
    rc = fminf(1.f + EPSILON_, fmaxf(1.f - EPSILON_, rc));
    float gp = clamp30(fminf(rho * a_n, rc * a_n));

    float rho2 = expf(fminf(llp - blp, 10.f));
    float r2c  = fminf(1.f + EPSILON_, fmaxf(1.f - EPSILON_, rho2));
    float lp = clamp30(fminf(rho2 * a_n, r2c * a_n));

    red[r]      = kl;
    red[16 + r] = kl * m;
    red[32 + r] = ent;
    red[48 + r] = gp;
    red[64 + r] = lp;
  }
  __syncthreads();
  if (tid == 0) {
    float s0=0.f, s1=0.f, s2=0.f, s3=0.f, s4=0.f;
    for (int r = 0; r < 16; ++r) {
      s0 += red[r]; s1 += red[16+r]; s2 += red[32+r];
      s3 += red[48+r]; s4 += red[64+r];
    }
    atomicAdd(&accum[0], s0);
    atomicAdd(&accum[1], s1);
    atomicAdd(&accum[2], s2);
    atomicAdd(&accum[6], s3);
    atomicAdd(&accum[7], s4);
  }
}

// =====================================================================
// Value: block = 32 obs rows, identical structure; layer3 uses a
// zero-padded 16-wide W2 (only n=0 valid), baseline = col 0.
// =====================================================================
__global__ __launch_bounds__(256, 3)
void value_kernel(const float* __restrict__ obs,
                  const float* __restrict__ rm,
                  const float* __restrict__ inv_std,
                  const u16* __restrict__ frag,
                  const float* __restrict__ b0,
                  const float* __restrict__ b1,
                  const float* __restrict__ b2,
                  float* __restrict__ baseline) {
  __shared__ __align__(16) u16 Xh[32 * SX], Xl[32 * SX];
  __shared__ __align__(16) u16 Hh[32 * SH], Hl[32 * SH];
  __shared__ float OUTT[32 * 16];

  const int tid  = threadIdx.x;
  const long row0 = (long)blockIdx.x * 32;
  const int lane = tid & 63;
  const int wv   = tid >> 6;
  const int mt   = wv >> 1;
  const int nth  = wv & 1;
  const int rowbase = mt * 16;
  const int lm = lane & 15;
  const int lq = lane >> 4;

  #pragma unroll
  for (int it = 0; it < 8; ++it) {
    int flat = it * 256 + tid;
    int rr = flat >> 6;
    int f  = flat & 63;
    float v = obs[(row0 + rr) * 64 + f];
    v = fminf(5.f, fmaxf(-5.f, (v - rm[f]) * inv_std[f]));
    u16 hi = f2bf(v);
    Xh[rr * SX + f] = hi;
    Xl[rr * SX + f] = f2bf(v - bf2f(hi));
  }
  __syncthreads();

  floatx4 acc[8];

  #pragma unroll
  for (int i = 0; i < 8; ++i) acc[i] = (floatx4){0.f, 0.f, 0.f, 0.f};
  {
    const short8* B0h = (const short8*)(frag + FR_W0V_HI);
    const short8* B0l = (const short8*)(frag + FR_W0V_LO);
    #pragma unroll
    for (int ks = 0; ks < 2; ++ks) {
      short8 Ah = *(const short8*)&Xh[(rowbase + lm) * SX + ks * 32 + lq * 8];
      short8 Al = *(const short8*)&Xl[(rowbase + lm) * SX + ks * 32 + lq * 8];
      #pragma unroll
      for (int nt = 0; nt < 8; ++nt) {
        int ntg = nth * 8 + nt;
        short8 Bh = B0h[(ntg * 2 + ks) * 64 + lane];
        short8 Bl = B0l[(ntg * 2 + ks) * 64 + lane];
        acc[nt] = __builtin_amdgcn_mfma_f32_16x16x32_bf16(Ah, Bh, acc[nt], 0, 0, 0);
        acc[nt] = __builtin_amdgcn_mfma_f32_16x16x32_bf16(Ah, Bl, acc[nt], 0, 0, 0);
        acc[nt] = __builtin_amdgcn_mfma_f32_16x16x32_bf16(Al, Bh, acc[nt], 0, 0, 0);
      }
    }
  }
  #pragma unroll
  for (int nt = 0; nt < 8; ++nt) {
    int col = (nth * 8 + nt) * 16 + lm;
    float bias = b0[col];
    #pragma unroll
    for (int reg = 0; reg < 4; ++reg) {
      int row = rowbase + lq * 4 + reg;
      float v = silu_f(acc[nt][reg] + bias);
      u16 hi = f2bf(v);
      Hh[row * SH + col] = hi;
      Hl[row * SH + col] = f2bf(v - bf2f(hi));
    }
  }
  __syncthreads();

  #pragma unroll
  for (int i = 0; i < 8; ++i) acc[i] = (floatx4){0.f, 0.f, 0.f, 0.f};
  {
    const short8* B1h = (const short8*)(frag + FR_W1V_HI);
    const short8* B1l = (const short8*)(frag + FR_W1V_LO);
    for (int ks = 0; ks < 8; ++ks) {
      short8 Ah = *(const short8*)&Hh[(rowbase + lm) * SH + ks * 32 + lq * 8];
      short8 Al = *(const short8*)&Hl[(rowbase + lm) * SH + ks * 32 + lq * 8];
      #pragma unroll
      for (int nt = 0; nt < 8; ++nt) {
        int ntg = nth * 8 + nt;
        short8 Bh = B1h[(ntg * 8 + ks) * 64 + lane];
        short8 Bl = B1l[(ntg * 8 + ks) * 64 + lane];
        acc[nt] = __builtin_amdgcn_mfma_f32_16x16x32_bf16(Ah, Bh, acc[nt], 0, 0, 0);
        acc[nt] = __builtin_amdgcn_mfma_f32_16x16x32_bf16(Ah, Bl, acc[nt], 0, 0, 0);
        acc[nt] = __builtin_amdgcn_mfma_f32_16x16x32_bf16(Al, Bh, acc[nt], 0, 0, 0);
      }
    }
  }
  __syncthreads();
  #pragma unroll
  for (int nt = 0; nt < 8; ++nt) {
    int col = (nth * 8 + nt) * 16 + lm;
    float bias = b1[col];
    #pragma unroll
    for (int reg = 0; reg < 4; ++reg) {
      int row = rowbase + lq * 4 + reg;
      float v = silu_f(acc[nt][reg] + bias);
      u16 hi = f2bf(v);
      Hh[row * SH + col] = hi;
      Hl[row * SH + col] = f2bf(v - bf2f(hi));
    }
  }
  __syncthreads();

  if (nth == 0) {
    floatx4 c3 = (floatx4){0.f, 0.f, 0.f, 0.f};
    const short8* B2h = (const short8*)(frag + FR_W2V_HI);
    const short8* B2l = (const short8*)(frag + FR_W2V_LO);
    for (int ks = 0; ks < 8; ++ks) {
      short8 Ah = *(const short8*)&Hh[(rowbase + lm) * SH + ks * 32 + lq * 8];
      short8 Al = *(const short8*)&Hl[(rowbase + lm) * SH + ks * 32 + lq * 8];
      short8 Bh = B2h[ks * 64 + lane];
      short8 Bl = B2l[ks * 64 + lane];
      c3 = __builtin_amdgcn_mfma_f32_16x16x32_bf16(Ah, Bh, c3, 0, 0, 0);
      c3 = __builtin_amdgcn_mfma_f32_16x16x32_bf16(Ah, Bl, c3, 0, 0, 0);
      c3 = __builtin_amdgcn_mfma_f32_16x16x32_bf16(Al, Bh, c3, 0, 0, 0);
    }
    #pragma unroll
    for (int reg = 0; reg < 4; ++reg) {
      int row = rowbase + lq * 4 + reg;
      OUTT[row * 16 + lm] = c3[reg];
    }
  }
  __syncthreads();

  if (tid < 32) baseline[row0 + tid] = OUTT[tid * 16] + b2[0];
}

// ---------------- GAE segmented scan (unchanged, verified) ----------------
__global__ void gae_phase1(const float* __restrict__ reward,
                           const float* __restrict__ done,
                           const float* __restrict__ trunc,
                           const float* __restrict__ baseline,
                           float* __restrict__ A, float* __restrict__ P) {
  int s = blockIdx.x, b = threadIdx.x;
  float Aa = 0.f, Pp = 1.f;
  for (int t = (s + 1) * 32 - 1; t >= s * 32; --t) {
    int idx = t * 256 + b;
    float r = reward[idx], d = done[idx], tr = trunc[idx];
    float tm = 1.f - tr;
    float te = d * tm;
    float bl = baseline[idx], bl1 = baseline[idx + 256];
    float g1 = GAMMA_ * (1.f - te);
    float delta = (r + g1 * bl1 - bl) * tm;
    float c = g1 * tm * LAM_;
    Aa = delta + c * Aa;
    Pp = c * Pp;
  }
  A[s * 256 + b] = Aa;
  P[s * 256 + b] = Pp;
}

__global__ void gae_phase2(const float* __restrict__ A,
                           const float* __restrict__ P,
                           float* __restrict__ seedv) {
  int b = threadIdx.x;
  float acc = 0.f;
  for (int s = 31; s >= 0; --s) {
    seedv[s * 256 + b] = acc;
    acc = A[s * 256 + b] + P[s * 256 + b] * acc;
  }
}

__global__ void gae_phase3(const float* __restrict__ reward,
                           const float* __restrict__ done,
                           const float* __restrict__ trunc,
                           const float* __restrict__ baseline,
                           const float* __restrict__ seedv,
                           float* __restrict__ adv,
                           float* __restrict__ accum) {
  __shared__ float red[12];
  int s = blockIdx.x, b = threadIdx.x;
  float acc = seedv[s * 256 + b];
  int tend = (s + 1) * 32;
  float vnext = baseline[tend * 256 + b];
  float vs_next = acc + vnext;
  float sa = 0.f, sa2 = 0.f, sv2 = 0.f;
  for (int t = tend - 1; t >= s * 32; --t) {
    int idx = t * 256 + b;
    float r = reward[idx], d = done[idx], tr = trunc[idx];
    float tm = 1.f - tr;
    float te = d * tm;
    float bl = baseline[idx];
    float g1 = GAMMA_ * (1.f - te);
    float delta = (r + g1 * vnext - bl) * tm;
    acc = delta + g1 * tm * LAM_ * acc;
    float at = (r + g1 * vs_next - bl) * tm;
    at = fminf(1e15f, fmaxf(-1e15f, at));
    adv[idx] = at;
    sa += at; sa2 += at * at;
    sv2 += fminf(acc * acc, 1e30f);
    vs_next = acc + bl;
    vnext = bl;
  }
  float v0 = sa, v1 = sa2, v2 = sv2;
  #pragma unroll
  for (int o = 32; o > 0; o >>= 1) {
    v0 += __shfl_down(v0, o, 64);
    v1 += __shfl_down(v1, o, 64);
    v2 += __shfl_down(v2, o, 64);
  }
  int lane = threadIdx.x & 63, w = threadIdx.x >> 6;
  if (lane == 0) { red[w] = v0; red[4 + w] = v1; red[8 + w] = v2; }
  __syncthreads();
  if (threadIdx.x == 0) {
    float s0=0.f, s1=0.f, s2=0.f;
    for (int q = 0; q < 4; ++q) { s0 += red[q]; s1 += red[4+q]; s2 += red[8+q]; }
    atomicAdd(&accum[3], s0);
    atomicAdd(&accum[4], s1);
    atomicAdd(&accum[5], s2);
  }
}

// ---------------- finalize ----------------
__global__ void finalize_kernel(const float* __restrict__ accum,
                                float* __restrict__ out) {
  float N = (float)ROWS_P;
  float kl_learner = accum[0] / N;
  float kl_guider  = accum[1] / N;
  float entropy    = accum[2] / N;
  float v_loss     = 0.25f * accum[5] / N;
  float gp_loss    = -accum[6] / N;
  float lp_loss    = -accum[7] / N;
  float learner_loss = kl_learner + lp_loss;      // ALPHA = 1
  float guider_loss  = kl_guider + gp_loss;
  float total = learner_loss + guider_loss + v_loss - 0.01f * entropy;
  out[0] = total;
  out[1] = guider_loss;
  out[2] = learner_loss;
  out[3] = kl_learner;
}

extern "C" void kernel_launch(void* const* d_in, const int* in_sizes, int n_in,
                              void* d_out, int out_size, void* d_ws, size_t ws_size,
                              hipStream_t stream) {
  (void)in_sizes; (void)n_in; (void)out_size; (void)ws_size;
  const float* obs    = (const float*)d_in[0];
  const float* pobs   = (const float*)d_in[1];
  const float* reward = (const float*)d_in[2];
  const float* done   = (const float*)d_in[3];
  const float* trunc  = (const float*)d_in[4];
  const float* logits = (const float*)d_in[5];
  const float* action = (const float*)d_in[6];
  const float* noise  = (const float*)d_in[7];
  const float* pw0 = (const float*)d_in[8];
  const float* pb0 = (const float*)d_in[9];
  const float* pw1 = (const float*)d_in[10];
  const float* pb1 = (const float*)d_in[11];
  const float* pw2 = (const float*)d_in[12];
  const float* pb2 = (const float*)d_in[13];
  const float* vw0 = (const float*)d_in[14];
  const float* vb0 = (const float*)d_in[15];
  const float* vw1 = (const float*)d_in[16];
  const float* vb1 = (const float*)d_in[17];
  const float* vw2 = (const float*)d_in[18];
  const float* vb2 = (const float*)d_in[19];
  const float* rm  = (const float*)d_in[20];
  const float* rv  = (const float*)d_in[21];

  u16*   frag  = (u16*)d_ws;
  float* fbase = (float*)d_ws + FR_TOTAL / 2;
  float* accum   = fbase + WS_ACC;
  float* inv_std = fbase + WS_INV;
  float* adv     = fbase + WS_ADV;
  float* base    = fbase + WS_BASE;
  float* gA      = fbase + WS_GA;
  float* gP      = fbase + WS_GP;
  float* gS      = fbase + WS_GS;
  float* out = (float*)d_out;

  prep_kernel<<<1, 256, 0, stream>>>(rv, inv_std, accum);
  convert_kernel<<<672, 256, 0, stream>>>(pw0, pw1, pw2, vw0, vw1, vw2, frag);

  value_kernel<<<(int)(ROWS_V / 32), 256, 0, stream>>>(
      obs, rm, inv_std, frag, vb0, vb1, vb2, base);

  gae_phase1<<<32, 256, 0, stream>>>(reward, done, trunc, base, gA, gP);
  gae_phase2<<<1, 256, 0, stream>>>(gA, gP, gS);
  gae_phase3<<<32, 256, 0, stream>>>(reward, done, trunc, base, gS, adv, accum);

  policy_kernel<<<(int)(ROWS_P / 16), 256, 0, stream>>>(
      obs, pobs, rm, inv_std, frag, pb0, pb1, pb2,
      logits, action, noise, adv, accum);

  finalize_kernel<<<1, 1, 0, stream>>>(accum, out);
}

// Round 4
// 1301.648 us; speedup vs baseline: 2.4617x; 1.2536x over previous
//
#include <hip/hip_runtime.h>
#include <math.h>

#define GAMMA_   0.97f
#define LAM_     0.95f
#define EPSILON_ 0.3f
#define HLOG2PI_ 0.91893853320467274f
#define LOG2C_   0.69314718055994531f
#define LOG1P2_  0.18232155679395463f
#define LOG0P8_  (-0.22314355131420976f)

typedef unsigned short u16;
typedef unsigned int   u32;
typedef __attribute__((ext_vector_type(8))) short short8;
typedef __attribute__((ext_vector_type(4))) float floatx4;

constexpr int  TT     = 1024;
constexpr long ROWS_P = (long)TT * 256;          // 262144
constexpr long ROWS_V = (long)(TT + 1) * 256;    // 262400

// ---- fragment workspace layout (u16 offsets from ws base) ----
// frag arrays: [NT][KS][64 lanes][8] bf16, one dwordx4 per (ntile,kstep,lane)
constexpr long FR_W0P_HI = 0;        // NT16 KS2  -> 16384
constexpr long FR_W0P_LO = 16384;
constexpr long FR_W1P_HI = 32768;    // NT16 KS8  -> 65536
constexpr long FR_W1P_LO = 98304;
constexpr long FR_W2P_HI = 163840;   // NT1  KS8  -> 4096
constexpr long FR_W2P_LO = 167936;
constexpr long FR_W0V_HI = 172032;
constexpr long FR_W0V_LO = 188416;
constexpr long FR_W1V_HI = 204800;
constexpr long FR_W1V_LO = 270336;
constexpr long FR_W2V_HI = 335872;
constexpr long FR_W2V_LO = 339968;
constexpr long FR_TOTAL  = 344064;   // u16 elems = 172032 floats

// ---- float workspace (offsets from (float*)ws + FR_TOTAL/2) ----
constexpr long WS_ACC  = 0;                 // 32
constexpr long WS_INV  = 32;                // 64
constexpr long WS_ADV  = 96;                // 262144
constexpr long WS_BASE = WS_ADV + ROWS_P;   // 262400
constexpr long WS_GA   = WS_BASE + ROWS_V;  // 8192
constexpr long WS_GP   = WS_GA + 8192;
constexpr long WS_GS   = WS_GP + 8192;

// accum slots: 0 kl_sum, 1 kl_m_sum, 2 ent_sum, 3 adv_sum, 4 adv2_sum,
//              5 vmx2_sum, 6 gp_sum, 7 lp_sum

__device__ __forceinline__ float softplus_f(float x) {
  return (x > 20.f) ? x : log1pf(expf(x));
}
__device__ __forceinline__ float silu_f(float x) {
  return x / (1.f + __expf(-x));
}
__device__ __forceinline__ float clamp30(float x) {
  return fminf(1e30f, fmaxf(-1e30f, x));
}
__device__ __forceinline__ u16 f2bf(float x) {      // RNE fp32 -> bf16
  u32 u = __float_as_uint(x);
  u32 r = (u + 0x7FFFu + ((u >> 16) & 1u)) >> 16;
  return (u16)r;
}
__device__ __forceinline__ float bf2f(u16 h) {
  return __uint_as_float(((u32)h) << 16);
}

// ---------------- prep ----------------
__global__ void prep_kernel(const float* __restrict__ rv,
                            float* __restrict__ inv_std,
                            float* __restrict__ accum) {
  int t = threadIdx.x;
  if (t < 32) accum[t] = 0.f;
  if (t < 64) {
    float var = rv[t] / 1000001.0f;
    var = fminf(1e6f, fmaxf(1e-6f, var));
    inv_std[t] = 1.f / sqrtf(var);
  }
}

// ---------------- weight -> split-bf16 MFMA fragments ----------------
__global__ void convert_kernel(const float* __restrict__ pw0,
                               const float* __restrict__ pw1,
                               const float* __restrict__ pw2,
                               const float* __restrict__ vw0,
                               const float* __restrict__ vw1,
                               const float* __restrict__ vw2,
                               u16* __restrict__ frag) {
  int idx = blockIdx.x * 256 + threadIdx.x;   // 0..172031
  const float* W; int kslog, K, nvalid; long hioff, looff; int e;
  if (idx < 16384)       { W = pw0; e = idx;          kslog = 1; K = 64;  nvalid = 256; hioff = FR_W0P_HI; looff = FR_W0P_LO; }
  else if (idx < 81920)  { W = pw1; e = idx - 16384;  kslog = 3; K = 256; nvalid = 256; hioff = FR_W1P_HI; looff = FR_W1P_LO; }
  else if (idx < 86016)  { W = pw2; e = idx - 81920;  kslog = 3; K = 256; nvalid = 16;  hioff = FR_W2P_HI; looff = FR_W2P_LO; }
  else if (idx < 102400) { W = vw0; e = idx - 86016;  kslog = 1; K = 64;  nvalid = 256; hioff = FR_W0V_HI; looff = FR_W0V_LO; }
  else if (idx < 167936) { W = vw1; e = idx - 102400; kslog = 3; K = 256; nvalid = 256; hioff = FR_W1V_HI; looff = FR_W1V_LO; }
  else                   { W = vw2; e = idx - 167936; kslog = 3; K = 256; nvalid = 1;   hioff = FR_W2V_HI; looff = FR_W2V_LO; }
  int j    = e & 7;
  int lane = (e >> 3) & 63;
  int ks   = (e >> 9) & ((1 << kslog) - 1);
  int nt   = e >> (9 + kslog);
  int n = nt * 16 + (lane & 15);
  int k = ks * 32 + ((lane >> 4) << 3) + j;
  float w = (n < nvalid) ? W[n * K + k] : 0.f;
  u16 hi = f2bf(w);
  frag[hioff + e] = hi;
  frag[looff + e] = f2bf(w - bf2f(hi));
}

// LDS strides (u16 units); multiples of 8 (16B-aligned rows)
constexpr int SX = 72;    // X row stride
constexpr int SH = 264;   // H row stride

// =====================================================================
// Policy: block = 32 obs rows (vrows 0..31) + same 32 pobs rows (32..63).
// 4 waves; wave wv owns ntile quarter (4 ntiles = 64 cols) x ALL 4 mtiles
// (reuse-4 on B fragments), with next-kstep B prefetch.
// =====================================================================
__global__ __launch_bounds__(256, 2)
void policy_kernel(const float* __restrict__ obs,
                   const float* __restrict__ pobs,
                   const float* __restrict__ rm,
                   const float* __restrict__ inv_std,
                   const u16* __restrict__ frag,
                   const float* __restrict__ b0,
                   const float* __restrict__ b1,
                   const float* __restrict__ b2,
                   const float* __restrict__ logits,
                   const float* __restrict__ action,
                   const float* __restrict__ noise,
                   const float* __restrict__ adv,
                   float* __restrict__ accum) {
  __shared__ __align__(16) u16 Hh[64 * SH], Hl[64 * SH];   // X aliases in
  __shared__ float OUTT[64 * 16];
  __shared__ float red[160];

  const int tid  = threadIdx.x;
  const long row0 = (long)blockIdx.x * 32;
  const int lane = tid & 63;
  const int wv   = tid >> 6;         // ntile quarter
  const int lm   = lane & 15;
  const int lq   = lane >> 4;

  u16* Xh = Hh;                      // X region aliases H (X dead after L1 MFMA)
  u16* Xl = Hl;

  // ---- stage normalized X (vrows 0..31 obs, 32..63 pobs), split bf16 ----
  #pragma unroll
  for (int it = 0; it < 16; ++it) {
    int flat = it * 256 + tid;       // 64 rows * 64 f
    int vr = flat >> 6;
    int f  = flat & 63;
    const float* src = (vr < 32) ? obs : pobs;
    float v = src[(row0 + (vr & 31)) * 64 + f];
    v = fminf(5.f, fmaxf(-5.f, (v - rm[f]) * inv_std[f]));
    u16 hi = f2bf(v);
    Xh[vr * SX + f] = hi;
    Xl[vr * SX + f] = f2bf(v - bf2f(hi));
  }
  __syncthreads();

  floatx4 acc[4][4];

  // ---- layer 1: K=64 (2 ksteps), all B frags upfront ----
  #pragma unroll
  for (int mt = 0; mt < 4; ++mt)
    #pragma unroll
    for (int nt = 0; nt < 4; ++nt) acc[mt][nt] = (floatx4){0.f,0.f,0.f,0.f};
  {
    const short8* B0h = (const short8*)(frag + FR_W0P_HI);
    const short8* B0l = (const short8*)(frag + FR_W0P_LO);
    short8 Bh[2][4], Bl[2][4];
    #pragma unroll
    for (int ks = 0; ks < 2; ++ks)
      #pragma unroll
      for (int nt = 0; nt < 4; ++nt) {
        int ntg = wv * 4 + nt;
        Bh[ks][nt] = B0h[(ntg * 2 + ks) * 64 + lane];
        Bl[ks][nt] = B0l[(ntg * 2 + ks) * 64 + lane];
      }
    #pragma unroll
    for (int ks = 0; ks < 2; ++ks) {
      short8 Ah[4], Al[4];
      #pragma unroll
      for (int mt = 0; mt < 4; ++mt) {
        Ah[mt] = *(const short8*)&Xh[(mt * 16 + lm) * SX + ks * 32 + lq * 8];
        Al[mt] = *(const short8*)&Xl[(mt * 16 + lm) * SX + ks * 32 + lq * 8];
      }
      #pragma unroll
      for (int mt = 0; mt < 4; ++mt)
        #pragma unroll
        for (int nt = 0; nt < 4; ++nt) {
          acc[mt][nt] = __builtin_amdgcn_mfma_f32_16x16x32_bf16(Ah[mt], Bh[ks][nt], acc[mt][nt], 0, 0, 0);
          acc[mt][nt] = __builtin_amdgcn_mfma_f32_16x16x32_bf16(Ah[mt], Bl[ks][nt], acc[mt][nt], 0, 0, 0);
          acc[mt][nt] = __builtin_amdgcn_mfma_f32_16x16x32_bf16(Al[mt], Bh[ks][nt], acc[mt][nt], 0, 0, 0);
        }
    }
  }
  __syncthreads();              // all waves done reading X (H1 aliases it)
  #pragma unroll
  for (int nt = 0; nt < 4; ++nt) {
    int col = (wv * 4 + nt) * 16 + lm;
    float bias = b0[col];
    #pragma unroll
    for (int mt = 0; mt < 4; ++mt)
      #pragma unroll
      for (int reg = 0; reg < 4; ++reg) {
        int row = mt * 16 + lq * 4 + reg;
        float v = silu_f(acc[mt][nt][reg] + bias);
        u16 hi = f2bf(v);
        Hh[row * SH + col] = hi;
        Hl[row * SH + col] = f2bf(v - bf2f(hi));
      }
  }
  __syncthreads();

  // ---- layer 2: K=256 (8 ksteps), B double-buffered ----
  #pragma unroll
  for (int mt = 0; mt < 4; ++mt)
    #pragma unroll
    for (int nt = 0; nt < 4; ++nt) acc[mt][nt] = (floatx4){0.f,0.f,0.f,0.f};
  {
    const short8* B1h = (const short8*)(frag + FR_W1P_HI);
    const short8* B1l = (const short8*)(frag + FR_W1P_LO);
    short8 Bh[4], Bl[4], Bhn[4], Bln[4];
    #pragma unroll
    for (int nt = 0; nt < 4; ++nt) {
      int ntg = wv * 4 + nt;
      Bh[nt] = B1h[(ntg * 8) * 64 + lane];
      Bl[nt] = B1l[(ntg * 8) * 64 + lane];
    }
    #pragma unroll
    for (int ks = 0; ks < 8; ++ks) {
      if (ks < 7) {
        #pragma unroll
        for (int nt = 0; nt < 4; ++nt) {
          int ntg = wv * 4 + nt;
          Bhn[nt] = B1h[(ntg * 8 + ks + 1) * 64 + lane];
          Bln[nt] = B1l[(ntg * 8 + ks + 1) * 64 + lane];
        }
      }
      short8 Ah[4], Al[4];
      #pragma unroll
      for (int mt = 0; mt < 4; ++mt) {
        Ah[mt] = *(const short8*)&Hh[(mt * 16 + lm) * SH + ks * 32 + lq * 8];
        Al[mt] = *(const short8*)&Hl[(mt * 16 + lm) * SH + ks * 32 + lq * 8];
      }
      #pragma unroll
      for (int mt = 0; mt < 4; ++mt)
        #pragma unroll
        for (int nt = 0; nt < 4; ++nt) {
          acc[mt][nt] = __builtin_amdgcn_mfma_f32_16x16x32_bf16(Ah[mt], Bh[nt], acc[mt][nt], 0, 0, 0);
          acc[mt][nt] = __builtin_amdgcn_mfma_f32_16x16x32_bf16(Ah[mt], Bl[nt], acc[mt][nt], 0, 0, 0);
          acc[mt][nt] = __builtin_amdgcn_mfma_f32_16x16x32_bf16(Al[mt], Bh[nt], acc[mt][nt], 0, 0, 0);
        }
      if (ks < 7) {
        #pragma unroll
        for (int nt = 0; nt < 4; ++nt) { Bh[nt] = Bhn[nt]; Bl[nt] = Bln[nt]; }
      }
    }
  }
  __syncthreads();              // all waves done reading H1
  #pragma unroll
  for (int nt = 0; nt < 4; ++nt) {
    int col = (wv * 4 + nt) * 16 + lm;
    float bias = b1[col];
    #pragma unroll
    for (int mt = 0; mt < 4; ++mt)
      #pragma unroll
      for (int reg = 0; reg < 4; ++reg) {
        int row = mt * 16 + lq * 4 + reg;
        float v = silu_f(acc[mt][nt][reg] + bias);
        u16 hi = f2bf(v);
        Hh[row * SH + col] = hi;
        Hl[row * SH + col] = f2bf(v - bf2f(hi));
      }
  }
  __syncthreads();

  // ---- layer 3: N=16, K=256; wave wv handles mtile wv ----
  {
    const short8* B2h = (const short8*)(frag + FR_W2P_HI);
    const short8* B2l = (const short8*)(frag + FR_W2P_LO);
    floatx4 c3 = (floatx4){0.f,0.f,0.f,0.f};
    #pragma unroll
    for (int ks = 0; ks < 8; ++ks) {
      short8 Ah = *(const short8*)&Hh[(wv * 16 + lm) * SH + ks * 32 + lq * 8];
      short8 Al = *(const short8*)&Hl[(wv * 16 + lm) * SH + ks * 32 + lq * 8];
      short8 Bh2 = B2h[ks * 64 + lane];
      short8 Bl2 = B2l[ks * 64 + lane];
      c3 = __builtin_amdgcn_mfma_f32_16x16x32_bf16(Ah, Bh2, c3, 0, 0, 0);
      c3 = __builtin_amdgcn_mfma_f32_16x16x32_bf16(Ah, Bl2, c3, 0, 0, 0);
      c3 = __builtin_amdgcn_mfma_f32_16x16x32_bf16(Al, Bh2, c3, 0, 0, 0);
    }
    float bias = b2[lm];
    #pragma unroll
    for (int reg = 0; reg < 4; ++reg)
      OUTT[(wv * 16 + lq * 4 + reg) * 16 + lm] = c3[reg] + bias;
  }
  __syncthreads();

  // ---- epilogue: 32 rows; vrow r = guider(obs), vrow 32+r = learner ----
  if (tid < 32) {
    int r = tid;
    long row = row0 + r;
    const float* arow = action + row * 8;
    const float* lrow = logits + row * 16;
    const float* nrow = noise  + row * 8;

    float glp = 0.f, llp = 0.f, kl = 0.f, blp = 0.f, ent = 0.f;
    #pragma unroll
    for (int d = 0; d < 8; ++d) {
      float gl  = OUTT[r * 16 + d];
      float gsr = OUTT[r * 16 + 8 + d];
      float ll  = OUTT[(32 + r) * 16 + d];
      float lsr = OUTT[(32 + r) * 16 + 8 + d];
      float gs = softplus_f(gsr) + 1e-3f;
      float ls = softplus_f(lsr) + 1e-3f;
      float a  = arow[d];
      float ldj = 2.f * (LOG2C_ - a - softplus_f(-2.f * a));
      float lgs = logf(gs), lls = logf(ls);
      float zg = (a - gl) / gs;
      float zl = (a - ll) / ls;
      glp += -0.5f * zg * zg - lgs - HLOG2PI_ - ldj;
      llp += -0.5f * zl * zl - lls - HLOG2PI_ - ldj;
      float ratio = gs / ls;
      float vr = ratio * ratio;
      float t1 = (gl - ll) / ls; t1 *= t1;
      kl += 0.5f * (vr + t1 - 1.f) - (lgs - lls);

      float loc = lrow[d], sr = lrow[8 + d];
      float sc  = softplus_f(sr) + 1e-3f;
      float lsc = logf(sc);
      float z   = (a - loc) / sc;
      blp += -0.5f * z * z - lsc - HLOG2PI_ - ldj;
      float dist  = loc + sc * nrow[d];
      float ldj_d = 2.f * (LOG2C_ - dist - softplus_f(-2.f * dist));
      ent += 0.5f + HLOG2PI_ + lsc + ldj_d;
    }
    kl *= 0.125f;
    kl  = clamp30(kl);
    ent = clamp30(ent);

    float diff = glp - llp;
    float m = (diff > LOG1P2_ || diff < LOG0P8_) ? 1.f : 0.f;

    float N = (float)ROWS_P;
    float sum = accum[3], sumsq = accum[4];
    float mean = sum / N;
    float var  = fmaxf((sumsq - sum * sum / N) / (N - 1.f), 0.f);
    float inv  = 1.f / (sqrtf(var) + 1e-5f);
    float a_n  = (adv[row] - mean) * inv;

    float rho = expf(fminf(glp - blp, 80.f));
    float cl  = fminf(LOG1P2_, fmaxf(LOG0P8_, diff));
    float rc  = expf(fminf(cl + llp - blp, 80.f));
    rc = fminf(1.f + EPSILON_, fmaxf(1.f - EPSILON_, rc));
    float gp = clamp30(fminf(rho * a_n, rc * a_n));

    float rho2 = expf(fminf(llp - blp, 10.f));
    float r2c  = fminf(1.f + EPSILON_, fmaxf(1.f - EPSILON_, rho2));
    float lp = clamp30(fminf(rho2 * a_n, r2c * a_n));

    red[r]       = kl;
    red[32 + r]  = kl * m;
    red[64 + r]  = ent;
    red[96 + r]  = gp;
    red[128 + r] = lp;
  }
  __syncthreads();
  if (tid == 0) {
    float s0=0.f, s1=0.f, s2=0.f, s3=0.f, s4=0.f;
    for (int r = 0; r < 32; ++r) {
      s0 += red[r]; s1 += red[32+r]; s2 += red[64+r];
      s3 += red[96+r]; s4 += red[128+r];
    }
    atomicAdd(&accum[0], s0);
    atomicAdd(&accum[1], s1);
    atomicAdd(&accum[2], s2);
    atomicAdd(&accum[6], s3);
    atomicAdd(&accum[7], s4);
  }
}

// =====================================================================
// Value: block = 64 obs rows, same reuse-4 structure; layer3 W2 is
// zero-padded to 16 wide (only n=0 valid); baseline = col 0.
// =====================================================================
__global__ __launch_bounds__(256, 2)
void value_kernel(const float* __restrict__ obs,
                  const float* __restrict__ rm,
                  const float* __restrict__ inv_std,
                  const u16* __restrict__ frag,
                  const float* __restrict__ b0,
                  const float* __restrict__ b1,
                  const float* __restrict__ b2,
                  float* __restrict__ baseline) {
  __shared__ __align__(16) u16 Hh[64 * SH], Hl[64 * SH];
  __shared__ float OUTT[64 * 16];

  const int tid  = threadIdx.x;
  const long row0 = (long)blockIdx.x * 64;
  const int lane = tid & 63;
  const int wv   = tid >> 6;
  const int lm   = lane & 15;
  const int lq   = lane >> 4;

  u16* Xh = Hh;
  u16* Xl = Hl;

  #pragma unroll
  for (int it = 0; it < 16; ++it) {
    int flat = it * 256 + tid;
    int vr = flat >> 6;
    int f  = flat & 63;
    float v = obs[(row0 + vr) * 64 + f];
    v = fminf(5.f, fmaxf(-5.f, (v - rm[f]) * inv_std[f]));
    u16 hi = f2bf(v);
    Xh[vr * SX + f] = hi;
    Xl[vr * SX + f] = f2bf(v - bf2f(hi));
  }
  __syncthreads();

  floatx4 acc[4][4];

  #pragma unroll
  for (int mt = 0; mt < 4; ++mt)
    #pragma unroll
    for (int nt = 0; nt < 4; ++nt) acc[mt][nt] = (floatx4){0.f,0.f,0.f,0.f};
  {
    const short8* B0h = (const short8*)(frag + FR_W0V_HI);
    const short8* B0l = (const short8*)(frag + FR_W0V_LO);
    short8 Bh[2][4], Bl[2][4];
    #pragma unroll
    for (int ks = 0; ks < 2; ++ks)
      #pragma unroll
      for (int nt = 0; nt < 4; ++nt) {
        int ntg = wv * 4 + nt;
        Bh[ks][nt] = B0h[(ntg * 2 + ks) * 64 + lane];
        Bl[ks][nt] = B0l[(ntg * 2 + ks) * 64 + lane];
      }
    #pragma unroll
    for (int ks = 0; ks < 2; ++ks) {
      short8 Ah[4], Al[4];
      #pragma unroll
      for (int mt = 0; mt < 4; ++mt) {
        Ah[mt] = *(const short8*)&Xh[(mt * 16 + lm) * SX + ks * 32 + lq * 8];
        Al[mt] = *(const short8*)&Xl[(mt * 16 + lm) * SX + ks * 32 + lq * 8];
      }
      #pragma unroll
      for (int mt = 0; mt < 4; ++mt)
        #pragma unroll
        for (int nt = 0; nt < 4; ++nt) {
          acc[mt][nt] = __builtin_amdgcn_mfma_f32_16x16x32_bf16(Ah[mt], Bh[ks][nt], acc[mt][nt], 0, 0, 0);
          acc[mt][nt] = __builtin_amdgcn_mfma_f32_16x16x32_bf16(Ah[mt], Bl[ks][nt], acc[mt][nt], 0, 0, 0);
          acc[mt][nt] = __builtin_amdgcn_mfma_f32_16x16x32_bf16(Al[mt], Bh[ks][nt], acc[mt][nt], 0, 0, 0);
        }
    }
  }
  __syncthreads();
  #pragma unroll
  for (int nt = 0; nt < 4; ++nt) {
    int col = (wv * 4 + nt) * 16 + lm;
    float bias = b0[col];
    #pragma unroll
    for (int mt = 0; mt < 4; ++mt)
      #pragma unroll
      for (int reg = 0; reg < 4; ++reg) {
        int row = mt * 16 + lq * 4 + reg;
        float v = silu_f(acc[mt][nt][reg] + bias);
        u16 hi = f2bf(v);
        Hh[row * SH + col] = hi;
        Hl[row * SH + col] = f2bf(v - bf2f(hi));
      }
  }
  __syncthreads();

  #pragma unroll
  for (int mt = 0; mt < 4; ++mt)
    #pragma unroll
    for (int nt = 0; nt < 4; ++nt) acc[mt][nt] = (floatx4){0.f,0.f,0.f,0.f};
  {
    const short8* B1h = (const short8*)(frag + FR_W1V_HI);
    const short8* B1l = (const short8*)(frag + FR_W1V_LO);
    short8 Bh[4], Bl[4], Bhn[4], Bln[4];
    #pragma unroll
    for (int nt = 0; nt < 4; ++nt) {
      int ntg = wv * 4 + nt;
      Bh[nt] = B1h[(ntg * 8) * 64 + lane];
      Bl[nt] = B1l[(ntg * 8) * 64 + lane];
    }
    #pragma unroll
    for (int ks = 0; ks < 8; ++ks) {
      if (ks < 7) {
        #pragma unroll
        for (int nt = 0; nt < 4; ++nt) {
          int ntg = wv * 4 + nt;
          Bhn[nt] = B1h[(ntg * 8 + ks + 1) * 64 + lane];
          Bln[nt] = B1l[(ntg * 8 + ks + 1) * 64 + lane];
        }
      }
      short8 Ah[4], Al[4];
      #pragma unroll
      for (int mt = 0; mt < 4; ++mt) {
        Ah[mt] = *(const short8*)&Hh[(mt * 16 + lm) * SH + ks * 32 + lq * 8];
        Al[mt] = *(const short8*)&Hl[(mt * 16 + lm) * SH + ks * 32 + lq * 8];
      }
      #pragma unroll
      for (int mt = 0; mt < 4; ++mt)
        #pragma unroll
        for (int nt = 0; nt < 4; ++nt) {
          acc[mt][nt] = __builtin_amdgcn_mfma_f32_16x16x32_bf16(Ah[mt], Bh[nt], acc[mt][nt], 0, 0, 0);
          acc[mt][nt] = __builtin_amdgcn_mfma_f32_16x16x32_bf16(Ah[mt], Bl[nt], acc[mt][nt], 0, 0, 0);
          acc[mt][nt] = __builtin_amdgcn_mfma_f32_16x16x32_bf16(Al[mt], Bh[nt], acc[mt][nt], 0, 0, 0);
        }
      if (ks < 7) {
        #pragma unroll
        for (int nt = 0; nt < 4; ++nt) { Bh[nt] = Bhn[nt]; Bl[nt] = Bln[nt]; }
      }
    }
  }
  __syncthreads();
  #pragma unroll
  for (int nt = 0; nt < 4; ++nt) {
    int col = (wv * 4 + nt) * 16 + lm;
    float bias = b1[col];
    #pragma unroll
    for (int mt = 0; mt < 4; ++mt)
      #pragma unroll
      for (int reg = 0; reg < 4; ++reg) {
        int row = mt * 16 + lq * 4 + reg;
        float v = silu_f(acc[mt][nt][reg] + bias);
        u16 hi = f2bf(v);
        Hh[row * SH + col] = hi;
        Hl[row * SH + col] = f2bf(v - bf2f(hi));
      }
  }
  __syncthreads();

  {
    const short8* B2h = (const short8*)(frag + FR_W2V_HI);
    const short8* B2l = (const short8*)(frag + FR_W2V_LO);
    floatx4 c3 = (floatx4){0.f,0.f,0.f,0.f};
    #pragma unroll
    for (int ks = 0; ks < 8; ++ks) {
      short8 Ah = *(const short8*)&Hh[(wv * 16 + lm) * SH + ks * 32 + lq * 8];
      short8 Al = *(const short8*)&Hl[(wv * 16 + lm) * SH + ks * 32 + lq * 8];
      short8 Bh2 = B2h[ks * 64 + lane];
      short8 Bl2 = B2l[ks * 64 + lane];
      c3 = __builtin_amdgcn_mfma_f32_16x16x32_bf16(Ah, Bh2, c3, 0, 0, 0);
      c3 = __builtin_amdgcn_mfma_f32_16x16x32_bf16(Ah, Bl2, c3, 0, 0, 0);
      c3 = __builtin_amdgcn_mfma_f32_16x16x32_bf16(Al, Bh2, c3, 0, 0, 0);
    }
    #pragma unroll
    for (int reg = 0; reg < 4; ++reg)
      OUTT[(wv * 16 + lq * 4 + reg) * 16 + lm] = c3[reg];
  }
  __syncthreads();

  if (tid < 64) baseline[row0 + tid] = OUTT[tid * 16] + b2[0];
}

// ---------------- GAE segmented scan (unchanged, verified) ----------------
__global__ void gae_phase1(const float* __restrict__ reward,
                           const float* __restrict__ done,
                           const float* __restrict__ trunc,
                           const float* __restrict__ baseline,
                           float* __restrict__ A, float* __restrict__ P) {
  int s = blockIdx.x, b = threadIdx.x;
  float Aa = 0.f, Pp = 1.f;
  for (int t = (s + 1) * 32 - 1; t >= s * 32; --t) {
    int idx = t * 256 + b;
    float r = reward[idx], d = done[idx], tr = trunc[idx];
    float tm = 1.f - tr;
    float te = d * tm;
    float bl = baseline[idx], bl1 = baseline[idx + 256];
    float g1 = GAMMA_ * (1.f - te);
    float delta = (r + g1 * bl1 - bl) * tm;
    float c = g1 * tm * LAM_;
    Aa = delta + c * Aa;
    Pp = c * Pp;
  }
  A[s * 256 + b] = Aa;
  P[s * 256 + b] = Pp;
}

__global__ void gae_phase2(const float* __restrict__ A,
                           const float* __restrict__ P,
                           float* __restrict__ seedv) {
  int b = threadIdx.x;
  float acc = 0.f;
  for (int s = 31; s >= 0; --s) {
    seedv[s * 256 + b] = acc;
    acc = A[s * 256 + b] + P[s * 256 + b] * acc;
  }
}

__global__ void gae_phase3(const float* __restrict__ reward,
                           const float* __restrict__ done,
                           const float* __restrict__ trunc,
                           const float* __restrict__ baseline,
                           const float* __restrict__ seedv,
                           float* __restrict__ adv,
                           float* __restrict__ accum) {
  __shared__ float red[12];
  int s = blockIdx.x, b = threadIdx.x;
  float acc = seedv[s * 256 + b];
  int tend = (s + 1) * 32;
  float vnext = baseline[tend * 256 + b];
  float vs_next = acc + vnext;
  float sa = 0.f, sa2 = 0.f, sv2 = 0.f;
  for (int t = tend - 1; t >= s * 32; --t) {
    int idx = t * 256 + b;
    float r = reward[idx], d = done[idx], tr = trunc[idx];
    float tm = 1.f - tr;
    float te = d * tm;
    float bl = baseline[idx];
    float g1 = GAMMA_ * (1.f - te);
    float delta = (r + g1 * vnext - bl) * tm;
    acc = delta + g1 * tm * LAM_ * acc;
    float at = (r + g1 * vs_next - bl) * tm;
    at = fminf(1e15f, fmaxf(-1e15f, at));
    adv[idx] = at;
    sa += at; sa2 += at * at;
    sv2 += fminf(acc * acc, 1e30f);
    vs_next = acc + bl;
    vnext = bl;
  }
  float v0 = sa, v1 = sa2, v2 = sv2;
  #pragma unroll
  for (int o = 32; o > 0; o >>= 1) {
    v0 += __shfl_down(v0, o, 64);
    v1 += __shfl_down(v1, o, 64);
    v2 += __shfl_down(v2, o, 64);
  }
  int lane = threadIdx.x & 63, w = threadIdx.x >> 6;
  if (lane == 0) { red[w] = v0; red[4 + w] = v1; red[8 + w] = v2; }
  __syncthreads();
  if (threadIdx.x == 0) {
    float s0=0.f, s1=0.f, s2=0.f;
    for (int q = 0; q < 4; ++q) { s0 += red[q]; s1 += red[4+q]; s2 += red[8+q]; }
    atomicAdd(&accum[3], s0);
    atomicAdd(&accum[4], s1);
    atomicAdd(&accum[5], s2);
  }
}

// ---------------- finalize ----------------
__global__ void finalize_kernel(const float* __restrict__ accum,
                                float* __restrict__ out) {
  float N = (float)ROWS_P;
  float kl_learner = accum[0] / N;
  float kl_guider  = accum[1] / N;
  float entropy    = accum[2] / N;
  float v_loss     = 0.25f * accum[5] / N;
  float gp_loss    = -accum[6] / N;
  float lp_loss    = -accum[7] / N;
  float learner_loss = kl_learner + lp_loss;      // ALPHA = 1
  float guider_loss  = kl_guider + gp_loss;
  float total = learner_loss + guider_loss + v_loss - 0.01f * entropy;
  out[0] = total;
  out[1] = guider_loss;
  out[2] = learner_loss;
  out[3] = kl_learner;
}

extern "C" void kernel_launch(void* const* d_in, const int* in_sizes, int n_in,
                              void* d_out, int out_size, void* d_ws, size_t ws_size,
                              hipStream_t stream) {
  (void)in_sizes; (void)n_in; (void)out_size; (void)ws_size;
  const float* obs    = (const float*)d_in[0];
  const float* pobs   = (const float*)d_in[1];
  const float* reward = (const float*)d_in[2];
  const float* done   = (const float*)d_in[3];
  const float* trunc  = (const float*)d_in[4];
  const float* logits = (const float*)d_in[5];
  const float* action = (const float*)d_in[6];
  const float* noise  = (const float*)d_in[7];
  const float* pw0 = (const float*)d_in[8];
  const float* pb0 = (const float*)d_in[9];
  const float* pw1 = (const float*)d_in[10];
  const float* pb1 = (const float*)d_in[11];
  const float* pw2 = (const float*)d_in[12];
  const float* pb2 = (const float*)d_in[13];
  const float* vw0 = (const float*)d_in[14];
  const float* vb0 = (const float*)d_in[15];
  const float* vw1 = (const float*)d_in[16];
  const float* vb1 = (const float*)d_in[17];
  const float* vw2 = (const float*)d_in[18];
  const float* vb2 = (const float*)d_in[19];
  const float* rm  = (const float*)d_in[20];
  const float* rv  = (const float*)d_in[21];

  u16*   frag  = (u16*)d_ws;
  float* fbase = (float*)d_ws + FR_TOTAL / 2;
  float* accum   = fbase + WS_ACC;
  float* inv_std = fbase + WS_INV;
  float* adv     = fbase + WS_ADV;
  float* base    = fbase + WS_BASE;
  float* gA      = fbase + WS_GA;
  float* gP      = fbase + WS_GP;
  float* gS      = fbase + WS_GS;
  float* out = (float*)d_out;

  prep_kernel<<<1, 256, 0, stream>>>(rv, inv_std, accum);
  convert_kernel<<<672, 256, 0, stream>>>(pw0, pw1, pw2, vw0, vw1, vw2, frag);

  value_kernel<<<(int)(ROWS_V / 64), 256, 0, stream>>>(
      obs, rm, inv_std, frag, vb0, vb1, vb2, base);

  gae_phase1<<<32, 256, 0, stream>>>(reward, done, trunc, base, gA, gP);
  gae_phase2<<<1, 256, 0, stream>>>(gA, gP, gS);
  gae_phase3<<<32, 256, 0, stream>>>(reward, done, trunc, base, gS, adv, accum);

  policy_kernel<<<(int)(ROWS_P / 32), 256, 0, stream>>>(
      obs, pobs, rm, inv_std, frag, pb0, pb1, pb2,
      logits, action, noise, adv, accum);

  finalize_kernel<<<1, 1, 0, stream>>>(accum, out);
}

// Round 5
// 869.206 us; speedup vs baseline: 3.6865x; 1.4975x over previous
//
#include <hip/hip_runtime.h>
#include <math.h>

#define GAMMA_   0.97f
#define LAM_     0.95f
#define EPSILON_ 0.3f
#define HLOG2PI_ 0.91893853320467274f
#define LOG2C_   0.69314718055994531f
#define LOG1P2_  0.18232155679395463f
#define LOG0P8_  (-0.22314355131420976f)

typedef unsigned short u16;
typedef unsigned int   u32;
typedef _Float16 half8 __attribute__((ext_vector_type(8)));
typedef __attribute__((ext_vector_type(4))) float floatx4;

constexpr int  TT     = 1024;
constexpr long ROWS_P = (long)TT * 256;          // 262144
constexpr long ROWS_V = (long)(TT + 1) * 256;    // 262400

// ---- fragment workspace layout (u16 offsets from ws base) ----
// frag arrays: [NT][KS][64 lanes][8] fp16, one dwordx4 per (ntile,kstep,lane)
constexpr long FR_W0P_HI = 0;        // NT16 KS2  -> 16384
constexpr long FR_W0P_LO = 16384;
constexpr long FR_W1P_HI = 32768;    // NT16 KS8  -> 65536
constexpr long FR_W1P_LO = 98304;
constexpr long FR_W2P_HI = 163840;   // NT1  KS8  -> 4096
constexpr long FR_W2P_LO = 167936;
constexpr long FR_W0V_HI = 172032;
constexpr long FR_W0V_LO = 188416;
constexpr long FR_W1V_HI = 204800;
constexpr long FR_W1V_LO = 270336;
constexpr long FR_W2V_HI = 335872;
constexpr long FR_W2V_LO = 339968;
constexpr long FR_TOTAL  = 344064;   // u16 elems

// ---- float workspace (offsets from (float*)ws + FR_TOTAL/2) ----
constexpr long WS_ACC  = 0;                 // 32
constexpr long WS_INV  = 32;                // 64
constexpr long WS_ADV  = 96;                // 262144
constexpr long WS_BASE = WS_ADV + ROWS_P;   // 262400
constexpr long WS_GA   = WS_BASE + ROWS_V;  // 8192
constexpr long WS_GP   = WS_GA + 8192;
constexpr long WS_GS   = WS_GP + 8192;

// accum slots: 0 kl_sum, 1 kl_m_sum, 2 ent_sum, 3 adv_sum, 4 adv2_sum,
//              5 vmx2_sum, 6 gp_sum, 7 lp_sum

__device__ __forceinline__ float softplus_f(float x) {
  return (x > 20.f) ? x : log1pf(expf(x));
}
__device__ __forceinline__ float silu_f(float x) {
  return x / (1.f + __expf(-x));
}
__device__ __forceinline__ float clamp30(float x) {
  return fminf(1e30f, fmaxf(-1e30f, x));
}

// ---------------- prep ----------------
__global__ void prep_kernel(const float* __restrict__ rv,
                            float* __restrict__ inv_std,
                            float* __restrict__ accum) {
  int t = threadIdx.x;
  if (t < 32) accum[t] = 0.f;
  if (t < 64) {
    float var = rv[t] / 1000001.0f;
    var = fminf(1e6f, fmaxf(1e-6f, var));
    inv_std[t] = 1.f / sqrtf(var);
  }
}

// ---------------- weight -> split-fp16 MFMA fragments ----------------
__global__ void convert_kernel(const float* __restrict__ pw0,
                               const float* __restrict__ pw1,
                               const float* __restrict__ pw2,
                               const float* __restrict__ vw0,
                               const float* __restrict__ vw1,
                               const float* __restrict__ vw2,
                               u16* __restrict__ frag) {
  int idx = blockIdx.x * 256 + threadIdx.x;   // 0..172031
  const float* W; int kslog, K, nvalid; long hioff, looff; int e;
  if (idx < 16384)       { W = pw0; e = idx;          kslog = 1; K = 64;  nvalid = 256; hioff = FR_W0P_HI; looff = FR_W0P_LO; }
  else if (idx < 81920)  { W = pw1; e = idx - 16384;  kslog = 3; K = 256; nvalid = 256; hioff = FR_W1P_HI; looff = FR_W1P_LO; }
  else if (idx < 86016)  { W = pw2; e = idx - 81920;  kslog = 3; K = 256; nvalid = 16;  hioff = FR_W2P_HI; looff = FR_W2P_LO; }
  else if (idx < 102400) { W = vw0; e = idx - 86016;  kslog = 1; K = 64;  nvalid = 256; hioff = FR_W0V_HI; looff = FR_W0V_LO; }
  else if (idx < 167936) { W = vw1; e = idx - 102400; kslog = 3; K = 256; nvalid = 256; hioff = FR_W1V_HI; looff = FR_W1V_LO; }
  else                   { W = vw2; e = idx - 167936; kslog = 3; K = 256; nvalid = 1;   hioff = FR_W2V_HI; looff = FR_W2V_LO; }
  int j    = e & 7;
  int lane = (e >> 3) & 63;
  int ks   = (e >> 9) & ((1 << kslog) - 1);
  int nt   = e >> (9 + kslog);
  int n = nt * 16 + (lane & 15);
  int k = ks * 32 + ((lane >> 4) << 3) + j;
  float w = (n < nvalid) ? W[n * K + k] : 0.f;
  _Float16 hi = (_Float16)w;
  _Float16 lo = (_Float16)(w - (float)hi);
  frag[hioff + e] = *(u16*)&hi;
  frag[looff + e] = *(u16*)&lo;
}

// LDS strides (fp16 units); multiples of 8 (16B-aligned rows)
constexpr int SX = 72;    // X row stride
constexpr int SH = 264;   // H row stride

// =====================================================================
// Policy: block = 32 obs rows (vrows 0..31) + same 32 pobs rows (32..63).
// 4 waves; wave wv owns ntile quarter (4 ntiles = 64 cols) x ALL 4 mtiles
// (reuse-4 on B), B double-buffered. fp16 1-plane acts, 2-plane weights.
// =====================================================================
__global__ __launch_bounds__(256, 3)
void policy_kernel(const float* __restrict__ obs,
                   const float* __restrict__ pobs,
                   const float* __restrict__ rm,
                   const float* __restrict__ inv_std,
                   const u16* __restrict__ frag,
                   const float* __restrict__ b0,
                   const float* __restrict__ b1,
                   const float* __restrict__ b2,
                   const float* __restrict__ logits,
                   const float* __restrict__ action,
                   const float* __restrict__ noise,
                   const float* __restrict__ adv,
                   float* __restrict__ accum) {
  __shared__ __align__(16) _Float16 H[64 * SH];   // 33792 B, X aliases in
  __shared__ float OUTT[64 * 16];
  __shared__ float red[160];

  const int tid  = threadIdx.x;
  const long row0 = (long)blockIdx.x * 32;
  const int lane = tid & 63;
  const int wv   = tid >> 6;         // ntile quarter
  const int lm   = lane & 15;
  const int lq   = lane >> 4;

  _Float16* X = H;                   // X dead after L1 MFMA

  // ---- stage normalized X (vrows 0..31 obs, 32..63 pobs), fp16 ----
  #pragma unroll
  for (int it = 0; it < 16; ++it) {
    int flat = it * 256 + tid;       // 64 rows * 64 f
    int vr = flat >> 6;
    int f  = flat & 63;
    const float* src = (vr < 32) ? obs : pobs;
    float v = src[(row0 + (vr & 31)) * 64 + f];
    v = fminf(5.f, fmaxf(-5.f, (v - rm[f]) * inv_std[f]));
    X[vr * SX + f] = (_Float16)v;
  }
  __syncthreads();

  floatx4 acc[4][4];

  // ---- layer 1: K=64 (2 ksteps) ----
  #pragma unroll
  for (int mt = 0; mt < 4; ++mt)
    #pragma unroll
    for (int nt = 0; nt < 4; ++nt) acc[mt][nt] = (floatx4){0.f,0.f,0.f,0.f};
  {
    const half8* B0h = (const half8*)(frag + FR_W0P_HI);
    const half8* B0l = (const half8*)(frag + FR_W0P_LO);
    half8 Bh[2][4], Bl[2][4];
    #pragma unroll
    for (int ks = 0; ks < 2; ++ks)
      #pragma unroll
      for (int nt = 0; nt < 4; ++nt) {
        int ntg = wv * 4 + nt;
        Bh[ks][nt] = B0h[(ntg * 2 + ks) * 64 + lane];
        Bl[ks][nt] = B0l[(ntg * 2 + ks) * 64 + lane];
      }
    #pragma unroll
    for (int ks = 0; ks < 2; ++ks) {
      half8 A[4];
      #pragma unroll
      for (int mt = 0; mt < 4; ++mt)
        A[mt] = *(const half8*)&X[(mt * 16 + lm) * SX + ks * 32 + lq * 8];
      #pragma unroll
      for (int mt = 0; mt < 4; ++mt)
        #pragma unroll
        for (int nt = 0; nt < 4; ++nt) {
          acc[mt][nt] = __builtin_amdgcn_mfma_f32_16x16x32_f16(A[mt], Bh[ks][nt], acc[mt][nt], 0, 0, 0);
          acc[mt][nt] = __builtin_amdgcn_mfma_f32_16x16x32_f16(A[mt], Bl[ks][nt], acc[mt][nt], 0, 0, 0);
        }
    }
  }
  __syncthreads();              // all waves done reading X (H1 aliases it)
  #pragma unroll
  for (int nt = 0; nt < 4; ++nt) {
    int col = (wv * 4 + nt) * 16 + lm;
    float bias = b0[col];
    #pragma unroll
    for (int mt = 0; mt < 4; ++mt)
      #pragma unroll
      for (int reg = 0; reg < 4; ++reg) {
        int row = mt * 16 + lq * 4 + reg;
        H[row * SH + col] = (_Float16)silu_f(acc[mt][nt][reg] + bias);
      }
  }
  __syncthreads();

  // ---- layer 2: K=256 (8 ksteps), B double-buffered ----
  #pragma unroll
  for (int mt = 0; mt < 4; ++mt)
    #pragma unroll
    for (int nt = 0; nt < 4; ++nt) acc[mt][nt] = (floatx4){0.f,0.f,0.f,0.f};
  {
    const half8* B1h = (const half8*)(frag + FR_W1P_HI);
    const half8* B1l = (const half8*)(frag + FR_W1P_LO);
    half8 Bh[4], Bl[4], Bhn[4], Bln[4];
    #pragma unroll
    for (int nt = 0; nt < 4; ++nt) {
      int ntg = wv * 4 + nt;
      Bh[nt] = B1h[(ntg * 8) * 64 + lane];
      Bl[nt] = B1l[(ntg * 8) * 64 + lane];
    }
    #pragma unroll
    for (int ks = 0; ks < 8; ++ks) {
      if (ks < 7) {
        #pragma unroll
        for (int nt = 0; nt < 4; ++nt) {
          int ntg = wv * 4 + nt;
          Bhn[nt] = B1h[(ntg * 8 + ks + 1) * 64 + lane];
          Bln[nt] = B1l[(ntg * 8 + ks + 1) * 64 + lane];
        }
      }
      half8 A[4];
      #pragma unroll
      for (int mt = 0; mt < 4; ++mt)
        A[mt] = *(const half8*)&H[(mt * 16 + lm) * SH + ks * 32 + lq * 8];
      #pragma unroll
      for (int mt = 0; mt < 4; ++mt)
        #pragma unroll
        for (int nt = 0; nt < 4; ++nt) {
          acc[mt][nt] = __builtin_amdgcn_mfma_f32_16x16x32_f16(A[mt], Bh[nt], acc[mt][nt], 0, 0, 0);
          acc[mt][nt] = __builtin_amdgcn_mfma_f32_16x16x32_f16(A[mt], Bl[nt], acc[mt][nt], 0, 0, 0);
        }
      if (ks < 7) {
        #pragma unroll
        for (int nt = 0; nt < 4; ++nt) { Bh[nt] = Bhn[nt]; Bl[nt] = Bln[nt]; }
      }
    }
  }
  __syncthreads();              // all waves done reading H1
  #pragma unroll
  for (int nt = 0; nt < 4; ++nt) {
    int col = (wv * 4 + nt) * 16 + lm;
    float bias = b1[col];
    #pragma unroll
    for (int mt = 0; mt < 4; ++mt)
      #pragma unroll
      for (int reg = 0; reg < 4; ++reg) {
        int row = mt * 16 + lq * 4 + reg;
        H[row * SH + col] = (_Float16)silu_f(acc[mt][nt][reg] + bias);
      }
  }
  __syncthreads();

  // ---- layer 3: N=16, K=256; wave wv handles mtile wv ----
  {
    const half8* B2h = (const half8*)(frag + FR_W2P_HI);
    const half8* B2l = (const half8*)(frag + FR_W2P_LO);
    floatx4 c3 = (floatx4){0.f,0.f,0.f,0.f};
    #pragma unroll
    for (int ks = 0; ks < 8; ++ks) {
      half8 A = *(const half8*)&H[(wv * 16 + lm) * SH + ks * 32 + lq * 8];
      half8 Bh2 = B2h[ks * 64 + lane];
      half8 Bl2 = B2l[ks * 64 + lane];
      c3 = __builtin_amdgcn_mfma_f32_16x16x32_f16(A, Bh2, c3, 0, 0, 0);
      c3 = __builtin_amdgcn_mfma_f32_16x16x32_f16(A, Bl2, c3, 0, 0, 0);
    }
    float bias = b2[lm];
    #pragma unroll
    for (int reg = 0; reg < 4; ++reg)
      OUTT[(wv * 16 + lq * 4 + reg) * 16 + lm] = c3[reg] + bias;
  }
  __syncthreads();

  // ---- epilogue: parallel over (row, d): tid = r*8 + d ----
  {
    int r = tid >> 3;          // 0..31
    int d = tid & 7;
    long row = row0 + r;

    float gl  = OUTT[r * 16 + d];
    float gsr = OUTT[r * 16 + 8 + d];
    float ll  = OUTT[(32 + r) * 16 + d];
    float lsr = OUTT[(32 + r) * 16 + 8 + d];
    float a   = action[row * 8 + d];
    float loc = logits[row * 16 + d];
    float sr  = logits[row * 16 + 8 + d];
    float nd  = noise[row * 8 + d];

    float gs = softplus_f(gsr) + 1e-3f;
    float ls = softplus_f(lsr) + 1e-3f;
    float sc = softplus_f(sr) + 1e-3f;
    float ldj = 2.f * (LOG2C_ - a - softplus_f(-2.f * a));
    float lgs = logf(gs), lls = logf(ls), lsc = logf(sc);
    float zg = (a - gl) / gs;
    float zl = (a - ll) / ls;
    float z  = (a - loc) / sc;
    float glp = -0.5f * zg * zg - lgs - HLOG2PI_ - ldj;
    float llp = -0.5f * zl * zl - lls - HLOG2PI_ - ldj;
    float blp = -0.5f * z * z - lsc - HLOG2PI_ - ldj;
    float ratio = gs / ls;
    float vr = ratio * ratio;
    float t1 = (gl - ll) / ls; t1 *= t1;
    float kl = 0.5f * (vr + t1 - 1.f) - (lgs - lls);
    float dist = loc + sc * nd;
    float ent = 0.5f + HLOG2PI_ + lsc
              + 2.f * (LOG2C_ - dist - softplus_f(-2.f * dist));

    // reduce over d (8 adjacent lanes)
    #pragma unroll
    for (int o = 4; o > 0; o >>= 1) {
      glp += __shfl_down(glp, o, 8);
      llp += __shfl_down(llp, o, 8);
      blp += __shfl_down(blp, o, 8);
      kl  += __shfl_down(kl, o, 8);
      ent += __shfl_down(ent, o, 8);
    }

    if (d == 0) {
      kl *= 0.125f;
      kl  = clamp30(kl);
      ent = clamp30(ent);

      float diff = glp - llp;
      float m = (diff > LOG1P2_ || diff < LOG0P8_) ? 1.f : 0.f;

      float N = (float)ROWS_P;
      float sum = accum[3], sumsq = accum[4];
      float mean = sum / N;
      float var  = fmaxf((sumsq - sum * sum / N) / (N - 1.f), 0.f);
      float inv  = 1.f / (sqrtf(var) + 1e-5f);
      float a_n  = (adv[row] - mean) * inv;

      float rho = expf(fminf(glp - blp, 80.f));
      float cl  = fminf(LOG1P2_, fmaxf(LOG0P8_, diff));
      float rc  = expf(fminf(cl + llp - blp, 80.f));
      rc = fminf(1.f + EPSILON_, fmaxf(1.f - EPSILON_, rc));
      float gp = clamp30(fminf(rho * a_n, rc * a_n));

      float rho2 = expf(fminf(llp - blp, 10.f));
      float r2c  = fminf(1.f + EPSILON_, fmaxf(1.f - EPSILON_, rho2));
      float lp = clamp30(fminf(rho2 * a_n, r2c * a_n));

      red[r]       = kl;
      red[32 + r]  = kl * m;
      red[64 + r]  = ent;
      red[96 + r]  = gp;
      red[128 + r] = lp;
    }
  }
  __syncthreads();
  if (tid < 32) {
    float s0 = red[tid], s1 = red[32 + tid], s2 = red[64 + tid];
    float s3 = red[96 + tid], s4 = red[128 + tid];
    #pragma unroll
    for (int o = 16; o > 0; o >>= 1) {
      s0 += __shfl_down(s0, o, 32);
      s1 += __shfl_down(s1, o, 32);
      s2 += __shfl_down(s2, o, 32);
      s3 += __shfl_down(s3, o, 32);
      s4 += __shfl_down(s4, o, 32);
    }
    if (tid == 0) {
      atomicAdd(&accum[0], s0);
      atomicAdd(&accum[1], s1);
      atomicAdd(&accum[2], s2);
      atomicAdd(&accum[6], s3);
      atomicAdd(&accum[7], s4);
    }
  }
}

// =====================================================================
// Value: block = 64 obs rows, same structure; layer3 W2 zero-padded to
// 16 wide (only n=0 valid); baseline = col 0.
// =====================================================================
__global__ __launch_bounds__(256, 3)
void value_kernel(const float* __restrict__ obs,
                  const float* __restrict__ rm,
                  const float* __restrict__ inv_std,
                  const u16* __restrict__ frag,
                  const float* __restrict__ b0,
                  const float* __restrict__ b1,
                  const float* __restrict__ b2,
                  float* __restrict__ baseline) {
  __shared__ __align__(16) _Float16 H[64 * SH];
  __shared__ float OUTT[64 * 16];

  const int tid  = threadIdx.x;
  const long row0 = (long)blockIdx.x * 64;
  const int lane = tid & 63;
  const int wv   = tid >> 6;
  const int lm   = lane & 15;
  const int lq   = lane >> 4;

  _Float16* X = H;

  #pragma unroll
  for (int it = 0; it < 16; ++it) {
    int flat = it * 256 + tid;
    int vr = flat >> 6;
    int f  = flat & 63;
    float v = obs[(row0 + vr) * 64 + f];
    v = fminf(5.f, fmaxf(-5.f, (v - rm[f]) * inv_std[f]));
    X[vr * SX + f] = (_Float16)v;
  }
  __syncthreads();

  floatx4 acc[4][4];

  #pragma unroll
  for (int mt = 0; mt < 4; ++mt)
    #pragma unroll
    for (int nt = 0; nt < 4; ++nt) acc[mt][nt] = (floatx4){0.f,0.f,0.f,0.f};
  {
    const half8* B0h = (const half8*)(frag + FR_W0V_HI);
    const half8* B0l = (const half8*)(frag + FR_W0V_LO);
    half8 Bh[2][4], Bl[2][4];
    #pragma unroll
    for (int ks = 0; ks < 2; ++ks)
      #pragma unroll
      for (int nt = 0; nt < 4; ++nt) {
        int ntg = wv * 4 + nt;
        Bh[ks][nt] = B0h[(ntg * 2 + ks) * 64 + lane];
        Bl[ks][nt] = B0l[(ntg * 2 + ks) * 64 + lane];
      }
    #pragma unroll
    for (int ks = 0; ks < 2; ++ks) {
      half8 A[4];
      #pragma unroll
      for (int mt = 0; mt < 4; ++mt)
        A[mt] = *(const half8*)&X[(mt * 16 + lm) * SX + ks * 32 + lq * 8];
      #pragma unroll
      for (int mt = 0; mt < 4; ++mt)
        #pragma unroll
        for (int nt = 0; nt < 4; ++nt) {
          acc[mt][nt] = __builtin_amdgcn_mfma_f32_16x16x32_f16(A[mt], Bh[ks][nt], acc[mt][nt], 0, 0, 0);
          acc[mt][nt] = __builtin_amdgcn_mfma_f32_16x16x32_f16(A[mt], Bl[ks][nt], acc[mt][nt], 0, 0, 0);
        }
    }
  }
  __syncthreads();
  #pragma unroll
  for (int nt = 0; nt < 4; ++nt) {
    int col = (wv * 4 + nt) * 16 + lm;
    float bias = b0[col];
    #pragma unroll
    for (int mt = 0; mt < 4; ++mt)
      #pragma unroll
      for (int reg = 0; reg < 4; ++reg) {
        int row = mt * 16 + lq * 4 + reg;
        H[row * SH + col] = (_Float16)silu_f(acc[mt][nt][reg] + bias);
      }
  }
  __syncthreads();

  #pragma unroll
  for (int mt = 0; mt < 4; ++mt)
    #pragma unroll
    for (int nt = 0; nt < 4; ++nt) acc[mt][nt] = (floatx4){0.f,0.f,0.f,0.f};
  {
    const half8* B1h = (const half8*)(frag + FR_W1V_HI);
    const half8* B1l = (const half8*)(frag + FR_W1V_LO);
    half8 Bh[4], Bl[4], Bhn[4], Bln[4];
    #pragma unroll
    for (int nt = 0; nt < 4; ++nt) {
      int ntg = wv * 4 + nt;
      Bh[nt] = B1h[(ntg * 8) * 64 + lane];
      Bl[nt] = B1l[(ntg * 8) * 64 + lane];
    }
    #pragma unroll
    for (int ks = 0; ks < 8; ++ks) {
      if (ks < 7) {
        #pragma unroll
        for (int nt = 0; nt < 4; ++nt) {
          int ntg = wv * 4 + nt;
          Bhn[nt] = B1h[(ntg * 8 + ks + 1) * 64 + lane];
          Bln[nt] = B1l[(ntg * 8 + ks + 1) * 64 + lane];
        }
      }
      half8 A[4];
      #pragma unroll
      for (int mt = 0; mt < 4; ++mt)
        A[mt] = *(const half8*)&H[(mt * 16 + lm) * SH + ks * 32 + lq * 8];
      #pragma unroll
      for (int mt = 0; mt < 4; ++mt)
        #pragma unroll
        for (int nt = 0; nt < 4; ++nt) {
          acc[mt][nt] = __builtin_amdgcn_mfma_f32_16x16x32_f16(A[mt], Bh[nt], acc[mt][nt], 0, 0, 0);
          acc[mt][nt] = __builtin_amdgcn_mfma_f32_16x16x32_f16(A[mt], Bl[nt], acc[mt][nt], 0, 0, 0);
        }
      if (ks < 7) {
        #pragma unroll
        for (int nt = 0; nt < 4; ++nt) { Bh[nt] = Bhn[nt]; Bl[nt] = Bln[nt]; }
      }
    }
  }
  __syncthreads();
  #pragma unroll
  for (int nt = 0; nt < 4; ++nt) {
    int col = (wv * 4 + nt) * 16 + lm;
    float bias = b1[col];
    #pragma unroll
    for (int mt = 0; mt < 4; ++mt)
      #pragma unroll
      for (int reg = 0; reg < 4; ++reg) {
        int row = mt * 16 + lq * 4 + reg;
        H[row * SH + col] = (_Float16)silu_f(acc[mt][nt][reg] + bias);
      }
  }
  __syncthreads();

  {
    const half8* B2h = (const half8*)(frag + FR_W2V_HI);
    const half8* B2l = (const half8*)(frag + FR_W2V_LO);
    floatx4 c3 = (floatx4){0.f,0.f,0.f,0.f};
    #pragma unroll
    for (int ks = 0; ks < 8; ++ks) {
      half8 A = *(const half8*)&H[(wv * 16 + lm) * SH + ks * 32 + lq * 8];
      half8 Bh2 = B2h[ks * 64 + lane];
      half8 Bl2 = B2l[ks * 64 + lane];
      c3 = __builtin_amdgcn_mfma_f32_16x16x32_f16(A, Bh2, c3, 0, 0, 0);
      c3 = __builtin_amdgcn_mfma_f32_16x16x32_f16(A, Bl2, c3, 0, 0, 0);
    }
    #pragma unroll
    for (int reg = 0; reg < 4; ++reg)
      OUTT[(wv * 16 + lq * 4 + reg) * 16 + lm] = c3[reg];
  }
  __syncthreads();

  if (tid < 64) baseline[row0 + tid] = OUTT[tid * 16] + b2[0];
}

// ---------------- GAE segmented scan (unchanged, verified) ----------------
__global__ void gae_phase1(const float* __restrict__ reward,
                           const float* __restrict__ done,
                           const float* __restrict__ trunc,
                           const float* __restrict__ baseline,
                           float* __restrict__ A, float* __restrict__ P) {
  int s = blockIdx.x, b = threadIdx.x;
  float Aa = 0.f, Pp = 1.f;
  for (int t = (s + 1) * 32 - 1; t >= s * 32; --t) {
    int idx = t * 256 + b;
    float r = reward[idx], d = done[idx], tr = trunc[idx];
    float tm = 1.f - tr;
    float te = d * tm;
    float bl = baseline[idx], bl1 = baseline[idx + 256];
    float g1 = GAMMA_ * (1.f - te);
    float delta = (r + g1 * bl1 - bl) * tm;
    float c = g1 * tm * LAM_;
    Aa = delta + c * Aa;
    Pp = c * Pp;
  }
  A[s * 256 + b] = Aa;
  P[s * 256 + b] = Pp;
}

__global__ void gae_phase2(const float* __restrict__ A,
                           const float* __restrict__ P,
                           float* __restrict__ seedv) {
  int b = threadIdx.x;
  float acc = 0.f;
  for (int s = 31; s >= 0; --s) {
    seedv[s * 256 + b] = acc;
    acc = A[s * 256 + b] + P[s * 256 + b] * acc;
  }
}

__global__ void gae_phase3(const float* __restrict__ reward,
                           const float* __restrict__ done,
                           const float* __restrict__ trunc,
                           const float* __restrict__ baseline,
                           const float* __restrict__ seedv,
                           float* __restrict__ adv,
                           float* __restrict__ accum) {
  __shared__ float red[12];
  int s = blockIdx.x, b = threadIdx.x;
  float acc = seedv[s * 256 + b];
  int tend = (s + 1) * 32;
  float vnext = baseline[tend * 256 + b];
  float vs_next = acc + vnext;
  float sa = 0.f, sa2 = 0.f, sv2 = 0.f;
  for (int t = tend - 1; t >= s * 32; --t) {
    int idx = t * 256 + b;
    float r = reward[idx], d = done[idx], tr = trunc[idx];
    float tm = 1.f - tr;
    float te = d * tm;
    float bl = baseline[idx];
    float g1 = GAMMA_ * (1.f - te);
    float delta = (r + g1 * vnext - bl) * tm;
    acc = delta + g1 * tm * LAM_ * acc;
    float at = (r + g1 * vs_next - bl) * tm;
    at = fminf(1e15f, fmaxf(-1e15f, at));
    adv[idx] = at;
    sa += at; sa2 += at * at;
    sv2 += fminf(acc * acc, 1e30f);
    vs_next = acc + bl;
    vnext = bl;
  }
  float v0 = sa, v1 = sa2, v2 = sv2;
  #pragma unroll
  for (int o = 32; o > 0; o >>= 1) {
    v0 += __shfl_down(v0, o, 64);
    v1 += __shfl_down(v1, o, 64);
    v2 += __shfl_down(v2, o, 64);
  }
  int lane = threadIdx.x & 63, w = threadIdx.x >> 6;
  if (lane == 0) { red[w] = v0; red[4 + w] = v1; red[8 + w] = v2; }
  __syncthreads();
  if (threadIdx.x == 0) {
    float s0=0.f, s1=0.f, s2=0.f;
    for (int q = 0; q < 4; ++q) { s0 += red[q]; s1 += red[4+q]; s2 += red[8+q]; }
    atomicAdd(&accum[3], s0);
    atomicAdd(&accum[4], s1);
    atomicAdd(&accum[5], s2);
  }
}

// ---------------- finalize ----------------
__global__ void finalize_kernel(const float* __restrict__ accum,
                                float* __restrict__ out) {
  float N = (float)ROWS_P;
  float kl_learner = accum[0] / N;
  float kl_guider  = accum[1] / N;
  float entropy    = accum[2] / N;
  float v_loss     = 0.25f * accum[5] / N;
  float gp_loss    = -accum[6] / N;
  float lp_loss    = -accum[7] / N;
  float learner_loss = kl_learner + lp_loss;      // ALPHA = 1
  float guider_loss  = kl_guider + gp_loss;
  float total = learner_loss + guider_loss + v_loss - 0.01f * entropy;
  out[0] = total;
  out[1] = guider_loss;
  out[2] = learner_loss;
  out[3] = kl_learner;
}

extern "C" void kernel_launch(void* const* d_in, const int* in_sizes, int n_in,
                              void* d_out, int out_size, void* d_ws, size_t ws_size,
                              hipStream_t stream) {
  (void)in_sizes; (void)n_in; (void)out_size; (void)ws_size;
  const float* obs    = (const float*)d_in[0];
  const float* pobs   = (const float*)d_in[1];
  const float* reward = (const float*)d_in[2];
  const float* done   = (const float*)d_in[3];
  const float* trunc  = (const float*)d_in[4];
  const float* logits = (const float*)d_in[5];
  const float* action = (const float*)d_in[6];
  const float* noise  = (const float*)d_in[7];
  const float* pw0 = (const float*)d_in[8];
  const float* pb0 = (const float*)d_in[9];
  const float* pw1 = (const float*)d_in[10];
  const float* pb1 = (const float*)d_in[11];
  const float* pw2 = (const float*)d_in[12];
  const float* pb2 = (const float*)d_in[13];
  const float* vw0 = (const float*)d_in[14];
  const float* vb0 = (const float*)d_in[15];
  const float* vw1 = (const float*)d_in[16];
  const float* vb1 = (const float*)d_in[17];
  const float* vw2 = (const float*)d_in[18];
  const float* vb2 = (const float*)d_in[19];
  const float* rm  = (const float*)d_in[20];
  const float* rv  = (const float*)d_in[21];

  u16*   frag  = (u16*)d_ws;
  float* fbase = (float*)d_ws + FR_TOTAL / 2;
  float* accum   = fbase + WS_ACC;
  float* inv_std = fbase + WS_INV;
  float* adv     = fbase + WS_ADV;
  float* base    = fbase + WS_BASE;
  float* gA      = fbase + WS_GA;
  float* gP      = fbase + WS_GP;
  float* gS      = fbase + WS_GS;
  float* out = (float*)d_out;

  prep_kernel<<<1, 256, 0, stream>>>(rv, inv_std, accum);
  convert_kernel<<<672, 256, 0, stream>>>(pw0, pw1, pw2, vw0, vw1, vw2, frag);

  value_kernel<<<(int)(ROWS_V / 64), 256, 0, stream>>>(
      obs, rm, inv_std, frag, vb0, vb1, vb2, base);

  gae_phase1<<<32, 256, 0, stream>>>(reward, done, trunc, base, gA, gP);
  gae_phase2<<<1, 256, 0, stream>>>(gA, gP, gS);
  gae_phase3<<<32, 256, 0, stream>>>(reward, done, trunc, base, gS, adv, accum);

  policy_kernel<<<(int)(ROWS_P / 32), 256, 0, stream>>>(
      obs, pobs, rm, inv_std, frag, pb0, pb1, pb2,
      logits, action, noise, adv, accum);

  finalize_kernel<<<1, 1, 0, stream>>>(accum, out);
}